// Round 1
// baseline (423.924 us; speedup 1.0000x reference)
//
#include <hip/hip_runtime.h>
#include <hip/hip_bf16.h>

// ---- problem constants ----
#define HIDN 1536
#define NH   24
#define NKV  6
#define HD   64
#define BB   2
#define SS   2048
#define MTOT (BB*SS)   // 4096

typedef __bf16 bf16x8 __attribute__((ext_vector_type(8)));
typedef float  f32x4  __attribute__((ext_vector_type(4)));
typedef unsigned short u16x8 __attribute__((ext_vector_type(8)));

__device__ inline float bf2f(unsigned short u) {
    unsigned v = (unsigned)u << 16; float f; __builtin_memcpy(&f, &v, 4); return f;
}
__device__ inline unsigned short f2bf(float f) {
    unsigned u; __builtin_memcpy(&u, &f, 4);
    u = (u + 0x7FFFu + ((u >> 16) & 1u)) >> 16;
    return (unsigned short)u;
}
__device__ inline void store_out(float* p, float v) { *p = v; }
__device__ inline void store_out(unsigned short* p, float v) { *p = f2bf(v); }

// ---------- cast f32 -> bf16, 4 elems/thread ----------
__global__ __launch_bounds__(256) void k_cast(const float* __restrict__ in,
                                              unsigned short* __restrict__ out, int n4) {
    int i = blockIdx.x * 256 + threadIdx.x;
    if (i >= n4) return;
    float4 v = reinterpret_cast<const float4*>(in)[i];
    ushort4 o;
    o.x = f2bf(v.x); o.y = f2bf(v.y); o.z = f2bf(v.z); o.w = f2bf(v.w);
    reinterpret_cast<ushort4*>(out)[i] = o;
}

// ---------- RoPE cos/sin table: [S][32] each ----------
__global__ __launch_bounds__(256) void k_rope_table(float* __restrict__ cosT,
                                                    float* __restrict__ sinT) {
    int i = blockIdx.x * 256 + threadIdx.x;
    if (i >= SS * 32) return;
    int s = i >> 5, f = i & 31;
    double inv = pow(10000.0, -(double)f / 32.0);
    double ang = (double)s * inv;
    cosT[i] = (float)cos(ang);
    sinT[i] = (float)sin(ang);
}

// ---------- GEMM: C[M,N] = A[M,K](bf16) @ Bt[N,K](bf16)^T ----------
// 128x128 tile, 4 waves of 64x64, BK=32, mfma_f32_16x16x32_bf16.
#define LDAP 56  // padded LDS row stride in elems (112B: 16B aligned, ~2-way banks)
template <typename OutT>
__global__ __launch_bounds__(256) void gemm_bt(const unsigned short* __restrict__ A,
                                               const unsigned short* __restrict__ Bt,
                                               OutT* __restrict__ C,
                                               int N, int K) {
    __shared__ unsigned short Alds[128 * LDAP];
    __shared__ unsigned short Blds[128 * LDAP];
    int t = threadIdx.x;
    int lane = t & 63, w = t >> 6;
    int m0 = blockIdx.y * 128, n0 = blockIdx.x * 128;
    int wm = (w >> 1) * 64, wn = (w & 1) * 64;
    int cidx = lane & 15, quad = lane >> 4;

    f32x4 zero = {0.f, 0.f, 0.f, 0.f};
    f32x4 acc[4][4];
#pragma unroll
    for (int mi = 0; mi < 4; ++mi)
#pragma unroll
        for (int ni = 0; ni < 4; ++ni) acc[mi][ni] = zero;

    for (int k0 = 0; k0 < K; k0 += 32) {
        __syncthreads();
#pragma unroll
        for (int i = 0; i < 2; ++i) {
            int c = t + 256 * i;
            int row = c >> 2, col = (c & 3) * 8;
            u16x8 av = *reinterpret_cast<const u16x8*>(A + (size_t)(m0 + row) * K + k0 + col);
            u16x8 bv = *reinterpret_cast<const u16x8*>(Bt + (size_t)(n0 + row) * K + k0 + col);
            *reinterpret_cast<u16x8*>(&Alds[row * LDAP + col]) = av;
            *reinterpret_cast<u16x8*>(&Blds[row * LDAP + col]) = bv;
        }
        __syncthreads();
        bf16x8 af[4], bfr[4];
#pragma unroll
        for (int mi = 0; mi < 4; ++mi)
            af[mi] = *reinterpret_cast<bf16x8*>(&Alds[(wm + mi * 16 + cidx) * LDAP + quad * 8]);
#pragma unroll
        for (int ni = 0; ni < 4; ++ni)
            bfr[ni] = *reinterpret_cast<bf16x8*>(&Blds[(wn + ni * 16 + cidx) * LDAP + quad * 8]);
#pragma unroll
        for (int mi = 0; mi < 4; ++mi)
#pragma unroll
            for (int ni = 0; ni < 4; ++ni)
                acc[mi][ni] = __builtin_amdgcn_mfma_f32_16x16x32_bf16(af[mi], bfr[ni],
                                                                      acc[mi][ni], 0, 0, 0);
    }
    // epilogue: C/D layout col=lane&15, row=(lane>>4)*4+reg  [m89-verified]
#pragma unroll
    for (int mi = 0; mi < 4; ++mi)
#pragma unroll
        for (int ni = 0; ni < 4; ++ni)
#pragma unroll
            for (int i = 0; i < 4; ++i) {
                int row = m0 + wm + mi * 16 + quad * 4 + i;
                int col = n0 + wn + ni * 16 + cidx;
                store_out(&C[(size_t)row * N + col], acc[mi][ni][i]);
            }
}

// ---------- RoPE + pack to [B,H,S,HD] bf16 ----------
__global__ __launch_bounds__(256) void k_rope_pack(const unsigned short* __restrict__ in,
                                                   const int* __restrict__ pos_ids,
                                                   const float* __restrict__ cosT,
                                                   const float* __restrict__ sinT,
                                                   unsigned short* __restrict__ out, int H) {
    int idx = blockIdx.x * 256 + threadIdx.x;
    int total = MTOT * H * 32;
    if (idx >= total) return;
    int i = idx & 31;
    int tmp = idx >> 5;
    int h = tmp % H;
    int m = tmp / H;
    int b = m >> 11, s = m & 2047;
    int pos = pos_ids[m];
    float c = cosT[pos * 32 + i], sn = sinT[pos * 32 + i];
    float x1 = bf2f(in[(size_t)m * (H * HD) + h * HD + i]);
    float x2 = bf2f(in[(size_t)m * (H * HD) + h * HD + 32 + i]);
    size_t o = (((size_t)(b * H + h)) * SS + s) * HD + i;
    out[o]      = f2bf(x1 * c - x2 * sn);
    out[o + 32] = f2bf(x2 * c + x1 * sn);
}

__global__ __launch_bounds__(256) void k_pack_v(const unsigned short* __restrict__ in,
                                                unsigned short* __restrict__ out) {
    int idx = blockIdx.x * 256 + threadIdx.x;  // MTOT*NKV*HD threads
    int d = idx & 63;
    int tmp = idx >> 6;
    int h = tmp % NKV;
    int m = tmp / NKV;
    int b = m >> 11, s = m & 2047;
    out[(((size_t)(b * NKV + h)) * SS + s) * HD + d] = in[(size_t)m * (NKV * HD) + h * HD + d];
}

// ---------- flash attention: 1 wave/block, 16 q-rows, kv tiles of 32 ----------
__global__ __launch_bounds__(64) void k_attn(const unsigned short* __restrict__ Qp,
                                             const unsigned short* __restrict__ Kp,
                                             const unsigned short* __restrict__ Vp,
                                             unsigned short* __restrict__ Op) {
    int qt = blockIdx.x, h = blockIdx.y, b = blockIdx.z;
    int kvh = h >> 2;  // G=4
    int lane = threadIdx.x;
    int cidx = lane & 15, quad = lane >> 4;
    int qbase = qt * 16;

    const unsigned short* qrow  = Qp + ((size_t)(b * NH + h) * SS + qbase) * HD;
    const unsigned short* kbase = Kp + ((size_t)(b * NKV + kvh) * SS) * HD;
    const unsigned short* vbase = Vp + ((size_t)(b * NKV + kvh) * SS) * HD;

    // Q A-fragments: row=lane&15, k=quad*8 (+32 per ka)
    bf16x8 qa[2];
#pragma unroll
    for (int ka = 0; ka < 2; ++ka)
        qa[ka] = *reinterpret_cast<const bf16x8*>(qrow + (size_t)cidx * HD + ka * 32 + quad * 8);

    f32x4 zero = {0.f, 0.f, 0.f, 0.f};
    f32x4 acc[4];
    float m_run[4], l_run[4];
#pragma unroll
    for (int i = 0; i < 4; ++i) { acc[i] = zero; m_run[i] = -1e30f; l_run[i] = 0.f; }

    __shared__ unsigned short Plds[16 * 32];

    int ntiles = ((qbase + 15) >> 5) + 1;
    for (int t = 0; t < ntiles; ++t) {
        int kvb = t * 32;
        // QK^T: two 16x16 output tiles (kv halves), contraction d=64 via 2 MFMA each
        f32x4 sc[2];
#pragma unroll
        for (int half = 0; half < 2; ++half) {
            f32x4 c = zero;
#pragma unroll
            for (int ka = 0; ka < 2; ++ka) {
                bf16x8 kb = *reinterpret_cast<const bf16x8*>(
                    kbase + (size_t)(kvb + half * 16 + cidx) * HD + ka * 32 + quad * 8);
                c = __builtin_amdgcn_mfma_f32_16x16x32_bf16(qa[ka], kb, c, 0, 0, 0);
            }
            sc[half] = c;
        }
        // scale + causal mask (C layout: col=cidx, row=quad*4+i)
        float mx[4];
#pragma unroll
        for (int i = 0; i < 4; ++i) {
            int row = qbase + quad * 4 + i;
            float s0 = sc[0][i] * 0.125f;
            float s1 = sc[1][i] * 0.125f;
            if (kvb + cidx > row)      s0 = -1e30f;
            if (kvb + 16 + cidx > row) s1 = -1e30f;
            sc[0][i] = s0; sc[1][i] = s1;
            mx[i] = fmaxf(s0, s1);
        }
        // row max across the 16 lanes holding this row's columns
#pragma unroll
        for (int d = 1; d < 16; d <<= 1)
#pragma unroll
            for (int i = 0; i < 4; ++i) mx[i] = fmaxf(mx[i], __shfl_xor(mx[i], d, 64));

        float scl[4], rsum[4];
#pragma unroll
        for (int i = 0; i < 4; ++i) {
            float mnew = fmaxf(m_run[i], mx[i]);
            scl[i] = __expf(m_run[i] - mnew);
            float p0 = __expf(sc[0][i] - mnew);
            float p1 = __expf(sc[1][i] - mnew);
            sc[0][i] = p0; sc[1][i] = p1;
            rsum[i] = p0 + p1;
            m_run[i] = mnew;
        }
#pragma unroll
        for (int d = 1; d < 16; d <<= 1)
#pragma unroll
            for (int i = 0; i < 4; ++i) rsum[i] += __shfl_xor(rsum[i], d, 64);
#pragma unroll
        for (int i = 0; i < 4; ++i) l_run[i] = l_run[i] * scl[i] + rsum[i];

        // P (C-layout) -> LDS -> A-fragment layout
#pragma unroll
        for (int i = 0; i < 4; ++i) {
            Plds[(quad * 4 + i) * 32 + cidx]      = f2bf(sc[0][i]);
            Plds[(quad * 4 + i) * 32 + 16 + cidx] = f2bf(sc[1][i]);
        }
        __syncthreads();
        bf16x8 pa = *reinterpret_cast<const bf16x8*>(&Plds[cidx * 32 + quad * 8]);

        // PV: out[16r x 64d] as 4 d-tiles; V B-frag: col=cidx(+16*dt), k=quad*8+j
#pragma unroll
        for (int dt = 0; dt < 4; ++dt) {
            u16x8 vv;
#pragma unroll
            for (int j = 0; j < 8; ++j)
                vv[j] = vbase[(size_t)(kvb + quad * 8 + j) * HD + dt * 16 + cidx];
            bf16x8 vb; __builtin_memcpy(&vb, &vv, 16);
            f32x4 a = acc[dt];
#pragma unroll
            for (int i = 0; i < 4; ++i) a[i] *= scl[i];
            acc[dt] = __builtin_amdgcn_mfma_f32_16x16x32_bf16(pa, vb, a, 0, 0, 0);
        }
        __syncthreads();
    }
    // epilogue: attn_out row-major [B*S, NH*HD] bf16
#pragma unroll
    for (int dt = 0; dt < 4; ++dt)
#pragma unroll
        for (int i = 0; i < 4; ++i) {
            int row = qbase + quad * 4 + i;
            size_t o = ((size_t)(b * SS) + row) * HIDN + h * HD + dt * 16 + cidx;
            Op[o] = f2bf(acc[dt][i] / l_run[i]);
        }
}

extern "C" void kernel_launch(void* const* d_in, const int* in_sizes, int n_in,
                              void* d_out, int out_size, void* d_ws, size_t ws_size,
                              hipStream_t stream) {
    (void)in_sizes; (void)n_in; (void)out_size; (void)ws_size;
    const float* h_f  = (const float*)d_in[0];
    const int*   pos  = (const int*)d_in[1];   // jax default x64-off -> int32
    const float* Wq_f = (const float*)d_in[2];
    const float* Wk_f = (const float*)d_in[3];
    const float* Wv_f = (const float*)d_in[4];
    const float* Wo_f = (const float*)d_in[5];
    float* out = (float*)d_out;

    char* ws = (char*)d_ws;
    size_t off = 0;
    auto alloc = [&](size_t bytes) -> void* {
        void* p = ws + off;
        off += (bytes + 255) & ~(size_t)255;
        return p;
    };
    unsigned short* h_bf  = (unsigned short*)alloc((size_t)MTOT * HIDN * 2);
    unsigned short* Wq_bf = (unsigned short*)alloc((size_t)NH * HD * HIDN * 2);
    unsigned short* Wk_bf = (unsigned short*)alloc((size_t)NKV * HD * HIDN * 2);
    unsigned short* Wv_bf = (unsigned short*)alloc((size_t)NKV * HD * HIDN * 2);
    unsigned short* Wo_bf = (unsigned short*)alloc((size_t)HIDN * NH * HD * 2);
    unsigned short* q_rm  = (unsigned short*)alloc((size_t)MTOT * NH * HD * 2);
    unsigned short* k_rm  = (unsigned short*)alloc((size_t)MTOT * NKV * HD * 2);
    unsigned short* v_rm  = (unsigned short*)alloc((size_t)MTOT * NKV * HD * 2);
    unsigned short* q_p   = (unsigned short*)alloc((size_t)MTOT * NH * HD * 2);
    unsigned short* k_p   = (unsigned short*)alloc((size_t)MTOT * NKV * HD * 2);
    unsigned short* v_p   = (unsigned short*)alloc((size_t)MTOT * NKV * HD * 2);
    unsigned short* a_out = (unsigned short*)alloc((size_t)MTOT * HIDN * 2);
    float* cosT = (float*)alloc((size_t)SS * 32 * 4);
    float* sinT = (float*)alloc((size_t)SS * 32 * 4);

    // casts (element counts all divisible by 4*256 except weights; bounds-checked anyway)
    k_cast<<<(MTOT * HIDN / 4 + 255) / 256, 256, 0, stream>>>(h_f, h_bf, MTOT * HIDN / 4);
    k_cast<<<(NH * HD * HIDN / 4 + 255) / 256, 256, 0, stream>>>(Wq_f, Wq_bf, NH * HD * HIDN / 4);
    k_cast<<<(NKV * HD * HIDN / 4 + 255) / 256, 256, 0, stream>>>(Wk_f, Wk_bf, NKV * HD * HIDN / 4);
    k_cast<<<(NKV * HD * HIDN / 4 + 255) / 256, 256, 0, stream>>>(Wv_f, Wv_bf, NKV * HD * HIDN / 4);
    k_cast<<<(HIDN * NH * HD / 4 + 255) / 256, 256, 0, stream>>>(Wo_f, Wo_bf, HIDN * NH * HD / 4);
    k_rope_table<<<(SS * 32 + 255) / 256, 256, 0, stream>>>(cosT, sinT);

    dim3 gq(HIDN / 128, MTOT / 128);       // (12, 32)
    dim3 gkv((NKV * HD) / 128, MTOT / 128);  // (3, 32)
    gemm_bt<unsigned short><<<gq, 256, 0, stream>>>(h_bf, Wq_bf, q_rm, NH * HD, HIDN);
    gemm_bt<unsigned short><<<gkv, 256, 0, stream>>>(h_bf, Wk_bf, k_rm, NKV * HD, HIDN);
    gemm_bt<unsigned short><<<gkv, 256, 0, stream>>>(h_bf, Wv_bf, v_rm, NKV * HD, HIDN);

    k_rope_pack<<<(MTOT * NH * 32) / 256, 256, 0, stream>>>(q_rm, pos, cosT, sinT, q_p, NH);
    k_rope_pack<<<(MTOT * NKV * 32) / 256, 256, 0, stream>>>(k_rm, pos, cosT, sinT, k_p, NKV);
    k_pack_v<<<(MTOT * NKV * HD) / 256, 256, 0, stream>>>(v_rm, v_p);

    k_attn<<<dim3(SS / 16, NH, BB), 64, 0, stream>>>(q_p, k_p, v_p, a_out);

    gemm_bt<float><<<gq, 256, 0, stream>>>(a_out, Wo_bf, out, HIDN, HIDN);
}

// Round 2
// 360.032 us; speedup vs baseline: 1.1775x; 1.1775x over previous
//
#include <hip/hip_runtime.h>
#include <hip/hip_bf16.h>

// ---- problem constants ----
#define HIDN 1536
#define NH   24
#define NKV  6
#define HD   64
#define BB   2
#define SS   2048
#define MTOT (BB*SS)   // 4096
#define NQKV 2304      // NH*HD + 2*NKV*HD

typedef __bf16 bf16x8 __attribute__((ext_vector_type(8)));
typedef float  f32x4  __attribute__((ext_vector_type(4)));
typedef unsigned short u16x8 __attribute__((ext_vector_type(8)));
typedef unsigned int   u32x2 __attribute__((ext_vector_type(2)));

typedef __attribute__((address_space(1))) const unsigned short as1_ushort;
typedef __attribute__((address_space(3))) unsigned short as3_ushort;

__device__ inline float bf2f(unsigned short u) {
    unsigned v = (unsigned)u << 16; float f; __builtin_memcpy(&f, &v, 4); return f;
}
__device__ inline unsigned short f2bf(float f) {
    unsigned u; __builtin_memcpy(&u, &f, 4);
    u = (u + 0x7FFFu + ((u >> 16) & 1u)) >> 16;
    return (unsigned short)u;
}
__device__ inline void store_out(float* p, float v) { *p = v; }
__device__ inline void store_out(unsigned short* p, float v) { *p = f2bf(v); }

// ---------- cast f32 -> bf16, 4 elems/thread ----------
__global__ __launch_bounds__(256) void k_cast(const float* __restrict__ in,
                                              unsigned short* __restrict__ out, int n4) {
    int i = blockIdx.x * 256 + threadIdx.x;
    if (i >= n4) return;
    float4 v = reinterpret_cast<const float4*>(in)[i];
    ushort4 o;
    o.x = f2bf(v.x); o.y = f2bf(v.y); o.z = f2bf(v.z); o.w = f2bf(v.w);
    reinterpret_cast<ushort4*>(out)[i] = o;
}

// ---------- RoPE cos/sin table: [S][32] each ----------
__global__ __launch_bounds__(256) void k_rope_table(float* __restrict__ cosT,
                                                    float* __restrict__ sinT) {
    int i = blockIdx.x * 256 + threadIdx.x;
    if (i >= SS * 32) return;
    int s = i >> 5, f = i & 31;
    double inv = pow(10000.0, -(double)f / 32.0);
    double ang = (double)s * inv;
    cosT[i] = (float)cos(ang);
    sinT[i] = (float)sin(ang);
}

// ---------- GEMM (m97 structure): C[M,N] = A[M,K](bf16) @ Bt[N,K](bf16)^T ----------
// 128x128 tile, 4 waves of 64x64, BK=32, global_load_lds width-16 staging, linear LDS.
template <typename OutT>
__global__ __launch_bounds__(256) void gemm_bt(const unsigned short* __restrict__ A,
                                               const unsigned short* __restrict__ Bt,
                                               OutT* __restrict__ C,
                                               int N, int K) {
    __shared__ unsigned short Alds[128 * 32];
    __shared__ unsigned short Blds[128 * 32];
    int t = threadIdx.x;
    int lane = t & 63, w = t >> 6;
    int m0 = blockIdx.y * 128, n0 = blockIdx.x * 128;
    int wm = (w >> 1) * 64, wn = (w & 1) * 64;
    int cidx = lane & 15, quad = lane >> 4;
    int srow = lane >> 2, scol = (lane & 3) * 8;   // staging: 16 rows x 32 cols per wave-chunk

    f32x4 zero = {0.f, 0.f, 0.f, 0.f};
    f32x4 acc[4][4];
#pragma unroll
    for (int mi = 0; mi < 4; ++mi)
#pragma unroll
        for (int ni = 0; ni < 4; ++ni) acc[mi][ni] = zero;

    for (int k0 = 0; k0 < K; k0 += 32) {
        __syncthreads();
#pragma unroll
        for (int c = 0; c < 2; ++c) {
            int chunk = w + c * 4;            // wave-uniform
            int row = chunk * 16 + srow;
            __builtin_amdgcn_global_load_lds(
                (as1_ushort*)(A + (size_t)(m0 + row) * K + k0 + scol),
                (as3_ushort*)&Alds[chunk * 512], 16, 0, 0);
            __builtin_amdgcn_global_load_lds(
                (as1_ushort*)(Bt + (size_t)(n0 + row) * K + k0 + scol),
                (as3_ushort*)&Blds[chunk * 512], 16, 0, 0);
        }
        __syncthreads();
        bf16x8 af[4], bfr[4];
#pragma unroll
        for (int mi = 0; mi < 4; ++mi)
            af[mi] = *reinterpret_cast<bf16x8*>(&Alds[(wm + mi * 16 + cidx) * 32 + quad * 8]);
#pragma unroll
        for (int ni = 0; ni < 4; ++ni)
            bfr[ni] = *reinterpret_cast<bf16x8*>(&Blds[(wn + ni * 16 + cidx) * 32 + quad * 8]);
#pragma unroll
        for (int mi = 0; mi < 4; ++mi)
#pragma unroll
            for (int ni = 0; ni < 4; ++ni)
                acc[mi][ni] = __builtin_amdgcn_mfma_f32_16x16x32_bf16(af[mi], bfr[ni],
                                                                      acc[mi][ni], 0, 0, 0);
    }
#pragma unroll
    for (int mi = 0; mi < 4; ++mi)
#pragma unroll
        for (int ni = 0; ni < 4; ++ni)
#pragma unroll
            for (int i = 0; i < 4; ++i) {
                int row = m0 + wm + mi * 16 + quad * 4 + i;
                int col = n0 + wn + ni * 16 + cidx;
                store_out(&C[(size_t)row * N + col], acc[mi][ni][i]);
            }
}

// ---------- RoPE + pack to [B,H,S,HD] bf16 (reads strided QKV gemm output) ----------
__global__ __launch_bounds__(256) void k_rope_pack(const unsigned short* __restrict__ in,
                                                   int istride, int col0,
                                                   const int* __restrict__ pos_ids,
                                                   const float* __restrict__ cosT,
                                                   const float* __restrict__ sinT,
                                                   unsigned short* __restrict__ out, int H) {
    int idx = blockIdx.x * 256 + threadIdx.x;
    int total = MTOT * H * 32;
    if (idx >= total) return;
    int i = idx & 31;
    int tmp = idx >> 5;
    int h = tmp % H;
    int m = tmp / H;
    int b = m >> 11, s = m & 2047;
    int pos = pos_ids[m];
    float c = cosT[pos * 32 + i], sn = sinT[pos * 32 + i];
    float x1 = bf2f(in[(size_t)m * istride + col0 + h * HD + i]);
    float x2 = bf2f(in[(size_t)m * istride + col0 + h * HD + 32 + i]);
    size_t o = (((size_t)(b * H + h)) * SS + s) * HD + i;
    out[o]      = f2bf(x1 * c - x2 * sn);
    out[o + 32] = f2bf(x2 * c + x1 * sn);
}

__global__ __launch_bounds__(256) void k_pack_v(const unsigned short* __restrict__ in,
                                                int istride, int col0,
                                                unsigned short* __restrict__ out) {
    int idx = blockIdx.x * 256 + threadIdx.x;  // MTOT*NKV*HD threads
    int d = idx & 63;
    int tmp = idx >> 6;
    int h = tmp % NKV;
    int m = tmp / NKV;
    int b = m >> 11, s = m & 2047;
    out[(((size_t)(b * NKV + h)) * SS + s) * HD + d] =
        in[(size_t)m * istride + col0 + h * HD + d];
}

// ---------- flash attention: 4 waves/block, QBLK=64, KVBLK=64 ----------
// V staged in LDS tiled [dt:4][kv4:16][4][16] for ds_read_b64_tr_b16; double-buffered.
// P per-wave in LDS [16][72] (pad 72 -> conflict-free A-frag reads).
#define TRR(dst, OFF) asm volatile("ds_read_b64_tr_b16 %0, %1 offset:" #OFF \
                                   : "=v"(dst) : "v"(va))

__global__ __launch_bounds__(256) void k_attn(const unsigned short* __restrict__ Qp,
                                              const unsigned short* __restrict__ Kp,
                                              const unsigned short* __restrict__ Vp,
                                              unsigned short* __restrict__ Op) {
    int qt = (int)gridDim.x - 1 - (int)blockIdx.x;  // heavy blocks dispatched first
    int h = blockIdx.y, b = blockIdx.z;
    int kvh = h >> 2;  // G=4
    int t = threadIdx.x, lane = t & 63, w = t >> 6;
    int cidx = lane & 15, quad = lane >> 4;
    int qbase = qt * 64;
    int qrow0 = qbase + w * 16;

    const unsigned short* qptr  = Qp + ((size_t)(b * NH + h) * SS + qrow0) * HD;
    const unsigned short* kbase = Kp + ((size_t)(b * NKV + kvh) * SS) * HD;
    const unsigned short* vbase = Vp + ((size_t)(b * NKV + kvh) * SS) * HD;

    __shared__ unsigned short Vt[2 * 4096];       // 2 x 8KB, tiled layout
    __shared__ unsigned short Plds[4][16 * 72];   // per-wave P

    bf16x8 qa[2];
#pragma unroll
    for (int ka = 0; ka < 2; ++ka)
        qa[ka] = *reinterpret_cast<const bf16x8*>(qptr + (size_t)cidx * HD + ka * 32 + quad * 8);

    f32x4 zero = {0.f, 0.f, 0.f, 0.f};
    f32x4 acc[4];
    float m_run[4], l_run[4];
#pragma unroll
    for (int i = 0; i < 4; ++i) { acc[i] = zero; m_run[i] = -1e30f; l_run[i] = 0.f; }

    // V staging: thread covers elems e0=t*8, e1=(t+256)*8 of the 64x64 tile (HD==64 -> glb off == e)
    int e0 = t * 8, e1 = (t + 256) * 8;
    int kv0 = e0 >> 6, d00 = e0 & 63;
    int kv1 = e1 >> 6, d01 = e1 & 63;
    int woff0 = (d00 >> 4) * 1024 + (kv0 >> 2) * 64 + (kv0 & 3) * 16 + (d00 & 15);
    int woff1 = (d01 >> 4) * 1024 + (kv1 >> 2) * 64 + (kv1 & 3) * 16 + (d01 & 15);

    // prologue: stage tile 0
    u16x8 vr0 = *reinterpret_cast<const u16x8*>(vbase + e0);
    u16x8 vr1 = *reinterpret_cast<const u16x8*>(vbase + e1);
    *reinterpret_cast<u16x8*>(&Vt[woff0]) = vr0;
    *reinterpret_cast<u16x8*>(&Vt[woff1]) = vr1;
    __syncthreads();

    unsigned vtb = (unsigned)(uintptr_t)(as3_ushort*)&Vt[0];
    unsigned va_base = vtb + (unsigned)(quad * 256 + cidx * 8);

    for (int tile = 0; tile <= qt; ++tile) {
        int cur = tile & 1;
        int kvb = tile * 64;
        // T14: issue next-tile V loads early
        if (tile < qt) {
            size_t nv = (size_t)(kvb + 64) * HD;
            vr0 = *reinterpret_cast<const u16x8*>(vbase + nv + e0);
            vr1 = *reinterpret_cast<const u16x8*>(vbase + nv + e1);
        }

        // ---- QK^T: 4 kv-subtiles of 16, K direct from global (L1/L2 shared by waves) ----
        f32x4 sc[4];
#pragma unroll
        for (int ht = 0; ht < 4; ++ht) {
            f32x4 c = zero;
#pragma unroll
            for (int ka = 0; ka < 2; ++ka) {
                bf16x8 kb = *reinterpret_cast<const bf16x8*>(
                    kbase + (size_t)(kvb + ht * 16 + cidx) * HD + ka * 32 + quad * 8);
                c = __builtin_amdgcn_mfma_f32_16x16x32_bf16(qa[ka], kb, c, 0, 0, 0);
            }
            sc[ht] = c;
        }

        // ---- scale + causal mask + row max ----
        bool diag = (tile == qt);
        float mx[4] = {-1e30f, -1e30f, -1e30f, -1e30f};
#pragma unroll
        for (int ht = 0; ht < 4; ++ht)
#pragma unroll
            for (int i = 0; i < 4; ++i) {
                float s = sc[ht][i] * 0.125f;
                if (diag && (kvb + ht * 16 + cidx > qrow0 + quad * 4 + i)) s = -1e30f;
                sc[ht][i] = s;
                mx[i] = fmaxf(mx[i], s);
            }
#pragma unroll
        for (int d = 1; d < 16; d <<= 1)
#pragma unroll
            for (int i = 0; i < 4; ++i) mx[i] = fmaxf(mx[i], __shfl_xor(mx[i], d, 64));

        // ---- online softmax ----
        float scl[4], rsum[4];
#pragma unroll
        for (int i = 0; i < 4; ++i) {
            float mnew = fmaxf(m_run[i], mx[i]);
            scl[i] = __expf(m_run[i] - mnew);
            m_run[i] = mnew;
            float rs = 0.f;
#pragma unroll
            for (int ht = 0; ht < 4; ++ht) {
                float p = __expf(sc[ht][i] - mnew);
                sc[ht][i] = p;
                rs += p;
            }
            rsum[i] = rs;
        }
#pragma unroll
        for (int d = 1; d < 16; d <<= 1)
#pragma unroll
            for (int i = 0; i < 4; ++i) rsum[i] += __shfl_xor(rsum[i], d, 64);
#pragma unroll
        for (int i = 0; i < 4; ++i) l_run[i] = l_run[i] * scl[i] + rsum[i];

        // ---- P -> per-wave LDS (C-layout write, A-frag read) ----
#pragma unroll
        for (int ht = 0; ht < 4; ++ht)
#pragma unroll
            for (int i = 0; i < 4; ++i)
                Plds[w][(quad * 4 + i) * 72 + ht * 16 + cidx] = f2bf(sc[ht][i]);
        bf16x8 pa0 = *reinterpret_cast<const bf16x8*>(&Plds[w][cidx * 72 + quad * 8]);
        bf16x8 pa1 = *reinterpret_cast<const bf16x8*>(&Plds[w][cidx * 72 + 32 + quad * 8]);

        // ---- rescale acc ----
#pragma unroll
        for (int dt = 0; dt < 4; ++dt)
#pragma unroll
            for (int i = 0; i < 4; ++i) acc[dt][i] *= scl[i];

        // ---- PV: 16 hardware-transpose reads of V, then 8 MFMAs ----
        unsigned va = va_base + (unsigned)(cur * 8192);
        u32x2 tr[4][2][2];
        TRR(tr[0][0][0], 0);    TRR(tr[0][0][1], 128);
        TRR(tr[0][1][0], 1024); TRR(tr[0][1][1], 1152);
        TRR(tr[1][0][0], 2048); TRR(tr[1][0][1], 2176);
        TRR(tr[1][1][0], 3072); TRR(tr[1][1][1], 3200);
        TRR(tr[2][0][0], 4096); TRR(tr[2][0][1], 4224);
        TRR(tr[2][1][0], 5120); TRR(tr[2][1][1], 5248);
        TRR(tr[3][0][0], 6144); TRR(tr[3][0][1], 6272);
        TRR(tr[3][1][0], 7168); TRR(tr[3][1][1], 7296);
        asm volatile("s_waitcnt lgkmcnt(0)" ::: "memory");
        __builtin_amdgcn_sched_barrier(0);
#pragma unroll
        for (int dt = 0; dt < 4; ++dt) {
            union { u32x2 a[2]; bf16x8 v; } u0, u1;
            u0.a[0] = tr[dt][0][0]; u0.a[1] = tr[dt][0][1];
            u1.a[0] = tr[dt][1][0]; u1.a[1] = tr[dt][1][1];
            acc[dt] = __builtin_amdgcn_mfma_f32_16x16x32_bf16(pa0, u0.v, acc[dt], 0, 0, 0);
            acc[dt] = __builtin_amdgcn_mfma_f32_16x16x32_bf16(pa1, u1.v, acc[dt], 0, 0, 0);
        }

        // T14 write-late: land next tile into other buffer
        if (tile < qt) {
            *reinterpret_cast<u16x8*>(&Vt[(cur ^ 1) * 4096 + woff0]) = vr0;
            *reinterpret_cast<u16x8*>(&Vt[(cur ^ 1) * 4096 + woff1]) = vr1;
        }
        __syncthreads();
    }

    // ---- epilogue ----
    float rl[4];
#pragma unroll
    for (int i = 0; i < 4; ++i) rl[i] = 1.f / l_run[i];
#pragma unroll
    for (int dt = 0; dt < 4; ++dt)
#pragma unroll
        for (int i = 0; i < 4; ++i) {
            int row = qrow0 + quad * 4 + i;
            size_t o = ((size_t)(b * SS) + row) * HIDN + h * HD + dt * 16 + cidx;
            Op[o] = f2bf(acc[dt][i] * rl[i]);
        }
}

extern "C" void kernel_launch(void* const* d_in, const int* in_sizes, int n_in,
                              void* d_out, int out_size, void* d_ws, size_t ws_size,
                              hipStream_t stream) {
    (void)in_sizes; (void)n_in; (void)out_size; (void)ws_size;
    const float* h_f  = (const float*)d_in[0];
    const int*   pos  = (const int*)d_in[1];
    const float* Wq_f = (const float*)d_in[2];
    const float* Wk_f = (const float*)d_in[3];
    const float* Wv_f = (const float*)d_in[4];
    const float* Wo_f = (const float*)d_in[5];
    float* out = (float*)d_out;

    char* ws = (char*)d_ws;
    size_t off = 0;
    auto alloc = [&](size_t bytes) -> void* {
        void* p = ws + off;
        off += (bytes + 255) & ~(size_t)255;
        return p;
    };
    unsigned short* h_bf   = (unsigned short*)alloc((size_t)MTOT * HIDN * 2);
    unsigned short* qkv_w  = (unsigned short*)alloc((size_t)NQKV * HIDN * 2);
    unsigned short* Wo_bf  = (unsigned short*)alloc((size_t)HIDN * NH * HD * 2);
    unsigned short* qkv_rm = (unsigned short*)alloc((size_t)MTOT * NQKV * 2);
    unsigned short* q_p    = (unsigned short*)alloc((size_t)MTOT * NH * HD * 2);
    unsigned short* k_p    = (unsigned short*)alloc((size_t)MTOT * NKV * HD * 2);
    unsigned short* v_p    = (unsigned short*)alloc((size_t)MTOT * NKV * HD * 2);
    unsigned short* a_out  = (unsigned short*)alloc((size_t)MTOT * HIDN * 2);
    float* cosT = (float*)alloc((size_t)SS * 32 * 4);
    float* sinT = (float*)alloc((size_t)SS * 32 * 4);

    k_cast<<<(MTOT * HIDN / 4 + 255) / 256, 256, 0, stream>>>(h_f, h_bf, MTOT * HIDN / 4);
    k_cast<<<(HIDN * HIDN / 4 + 255) / 256, 256, 0, stream>>>(Wq_f, qkv_w, HIDN * HIDN / 4);
    k_cast<<<(NKV * HD * HIDN / 4 + 255) / 256, 256, 0, stream>>>(
        Wk_f, qkv_w + (size_t)HIDN * HIDN, NKV * HD * HIDN / 4);
    k_cast<<<(NKV * HD * HIDN / 4 + 255) / 256, 256, 0, stream>>>(
        Wv_f, qkv_w + (size_t)(HIDN + NKV * HD) * HIDN, NKV * HD * HIDN / 4);
    k_cast<<<(HIDN * NH * HD / 4 + 255) / 256, 256, 0, stream>>>(Wo_f, Wo_bf, HIDN * NH * HD / 4);
    k_rope_table<<<(SS * 32 + 255) / 256, 256, 0, stream>>>(cosT, sinT);

    // fused QKV projection: [4096 x 1536] @ [2304 x 1536]^T
    gemm_bt<unsigned short><<<dim3(NQKV / 128, MTOT / 128), 256, 0, stream>>>(
        h_bf, qkv_w, qkv_rm, NQKV, HIDN);

    k_rope_pack<<<(MTOT * NH * 32) / 256, 256, 0, stream>>>(
        qkv_rm, NQKV, 0, pos, cosT, sinT, q_p, NH);
    k_rope_pack<<<(MTOT * NKV * 32) / 256, 256, 0, stream>>>(
        qkv_rm, NQKV, NH * HD, pos, cosT, sinT, k_p, NKV);
    k_pack_v<<<(MTOT * NKV * HD) / 256, 256, 0, stream>>>(
        qkv_rm, NQKV, NH * HD + NKV * HD, v_p);

    k_attn<<<dim3(SS / 64, NH, BB), 256, 0, stream>>>(q_p, k_p, v_p, a_out);

    gemm_bt<float><<<dim3(HIDN / 128, MTOT / 128), 256, 0, stream>>>(
        a_out, Wo_bf, out, HIDN, HIDN);
}

// Round 3
// 299.966 us; speedup vs baseline: 1.4132x; 1.2002x over previous
//
#include <hip/hip_runtime.h>
#include <hip/hip_bf16.h>

// ---- problem constants ----
#define HIDN 1536
#define NH   24
#define NKV  6
#define HD   64
#define BB   2
#define SS   2048
#define MTOT (BB*SS)   // 4096
#define NQKV 2304      // NH*HD + 2*NKV*HD
#define NCHUNK 80      // sum over qt=0..31 of (qt/8+1)

typedef __bf16 bf16x8 __attribute__((ext_vector_type(8)));
typedef float  f32x4  __attribute__((ext_vector_type(4)));
typedef unsigned short u16x8 __attribute__((ext_vector_type(8)));
typedef unsigned int   u32x2 __attribute__((ext_vector_type(2)));

typedef __attribute__((address_space(1))) const unsigned short as1_ushort;
typedef __attribute__((address_space(3))) unsigned short as3_ushort;

__device__ inline float bf2f(unsigned short u) {
    unsigned v = (unsigned)u << 16; float f; __builtin_memcpy(&f, &v, 4); return f;
}
__device__ inline unsigned short f2bf(float f) {
    unsigned u; __builtin_memcpy(&u, &f, 4);
    u = (u + 0x7FFFu + ((u >> 16) & 1u)) >> 16;
    return (unsigned short)u;
}
__device__ inline unsigned cvt_pk_bf16(float lo, float hi) {
    unsigned r;
    asm("v_cvt_pk_bf16_f32 %0, %1, %2" : "=v"(r) : "v"(lo), "v"(hi));
    return r;
}
__device__ inline void store_out(float* p, float v) { *p = v; }
__device__ inline void store_out(unsigned short* p, float v) { *p = f2bf(v); }

// ---------- cast f32 -> bf16, 4 elems/thread ----------
__global__ __launch_bounds__(256) void k_cast(const float* __restrict__ in,
                                              unsigned short* __restrict__ out, int n4) {
    int i = blockIdx.x * 256 + threadIdx.x;
    if (i >= n4) return;
    float4 v = reinterpret_cast<const float4*>(in)[i];
    ushort4 o;
    o.x = f2bf(v.x); o.y = f2bf(v.y); o.z = f2bf(v.z); o.w = f2bf(v.w);
    reinterpret_cast<ushort4*>(out)[i] = o;
}

// ---------- RoPE cos/sin table: [S][32] each ----------
__global__ __launch_bounds__(256) void k_rope_table(float* __restrict__ cosT,
                                                    float* __restrict__ sinT) {
    int i = blockIdx.x * 256 + threadIdx.x;
    if (i >= SS * 32) return;
    int s = i >> 5, f = i & 31;
    double inv = pow(10000.0, -(double)f / 32.0);
    double ang = (double)s * inv;
    cosT[i] = (float)cos(ang);
    sinT[i] = (float)sin(ang);
}

// ---------- GEMM (m97 structure): C[M,N] = A[M,K](bf16) @ Bt[N,K](bf16)^T ----------
template <typename OutT>
__global__ __launch_bounds__(256) void gemm_bt(const unsigned short* __restrict__ A,
                                               const unsigned short* __restrict__ Bt,
                                               OutT* __restrict__ C,
                                               int N, int K) {
    __shared__ unsigned short Alds[128 * 32];
    __shared__ unsigned short Blds[128 * 32];
    int t = threadIdx.x;
    int lane = t & 63, w = t >> 6;
    int m0 = blockIdx.y * 128, n0 = blockIdx.x * 128;
    int wm = (w >> 1) * 64, wn = (w & 1) * 64;
    int cidx = lane & 15, quad = lane >> 4;
    int srow = lane >> 2, scol = (lane & 3) * 8;

    f32x4 zero = {0.f, 0.f, 0.f, 0.f};
    f32x4 acc[4][4];
#pragma unroll
    for (int mi = 0; mi < 4; ++mi)
#pragma unroll
        for (int ni = 0; ni < 4; ++ni) acc[mi][ni] = zero;

    for (int k0 = 0; k0 < K; k0 += 32) {
        __syncthreads();
#pragma unroll
        for (int c = 0; c < 2; ++c) {
            int chunk = w + c * 4;
            int row = chunk * 16 + srow;
            __builtin_amdgcn_global_load_lds(
                (as1_ushort*)(A + (size_t)(m0 + row) * K + k0 + scol),
                (as3_ushort*)&Alds[chunk * 512], 16, 0, 0);
            __builtin_amdgcn_global_load_lds(
                (as1_ushort*)(Bt + (size_t)(n0 + row) * K + k0 + scol),
                (as3_ushort*)&Blds[chunk * 512], 16, 0, 0);
        }
        __syncthreads();
        bf16x8 af[4], bfr[4];
#pragma unroll
        for (int mi = 0; mi < 4; ++mi)
            af[mi] = *reinterpret_cast<bf16x8*>(&Alds[(wm + mi * 16 + cidx) * 32 + quad * 8]);
#pragma unroll
        for (int ni = 0; ni < 4; ++ni)
            bfr[ni] = *reinterpret_cast<bf16x8*>(&Blds[(wn + ni * 16 + cidx) * 32 + quad * 8]);
#pragma unroll
        for (int mi = 0; mi < 4; ++mi)
#pragma unroll
            for (int ni = 0; ni < 4; ++ni)
                acc[mi][ni] = __builtin_amdgcn_mfma_f32_16x16x32_bf16(af[mi], bfr[ni],
                                                                      acc[mi][ni], 0, 0, 0);
    }
#pragma unroll
    for (int mi = 0; mi < 4; ++mi)
#pragma unroll
        for (int ni = 0; ni < 4; ++ni)
#pragma unroll
            for (int i = 0; i < 4; ++i) {
                int row = m0 + wm + mi * 16 + quad * 4 + i;
                int col = n0 + wn + ni * 16 + cidx;
                store_out(&C[(size_t)row * N + col], acc[mi][ni][i]);
            }
}

// ---------- RoPE + pack to [B,H,S,HD] bf16 (with optional pre-scale) ----------
__global__ __launch_bounds__(256) void k_rope_pack(const unsigned short* __restrict__ in,
                                                   int istride, int col0,
                                                   const int* __restrict__ pos_ids,
                                                   const float* __restrict__ cosT,
                                                   const float* __restrict__ sinT,
                                                   unsigned short* __restrict__ out, int H,
                                                   float scale) {
    int idx = blockIdx.x * 256 + threadIdx.x;
    int total = MTOT * H * 32;
    if (idx >= total) return;
    int i = idx & 31;
    int tmp = idx >> 5;
    int h = tmp % H;
    int m = tmp / H;
    int b = m >> 11, s = m & 2047;
    int pos = pos_ids[m];
    float c = cosT[pos * 32 + i], sn = sinT[pos * 32 + i];
    float x1 = bf2f(in[(size_t)m * istride + col0 + h * HD + i]);
    float x2 = bf2f(in[(size_t)m * istride + col0 + h * HD + 32 + i]);
    size_t o = (((size_t)(b * H + h)) * SS + s) * HD + i;
    out[o]      = f2bf((x1 * c - x2 * sn) * scale);
    out[o + 32] = f2bf((x2 * c + x1 * sn) * scale);
}

__global__ __launch_bounds__(256) void k_pack_v(const unsigned short* __restrict__ in,
                                                int istride, int col0,
                                                unsigned short* __restrict__ out) {
    int idx = blockIdx.x * 256 + threadIdx.x;
    int d = idx & 63;
    int tmp = idx >> 6;
    int h = tmp % NKV;
    int m = tmp / NKV;
    int b = m >> 11, s = m & 2047;
    out[(((size_t)(b * NKV + h)) * SS + s) * HD + d] =
        in[(size_t)m * istride + col0 + h * HD + d];
}

// ---------- split-KV flash attention ----------
// grid.x = 80 chunk-blocks per (b,h): qt in [0,32), chunk c covers kv [c*512,(c+1)*512).
// 4 waves x 16 q-rows. Partials: acc bf16 [p][64][64], (m,l) f32 [p][64][2].
#define TRR(dst, ADDR, OFF) asm volatile("ds_read_b64_tr_b16 %0, %1 offset:" #OFF \
                                         : "=v"(dst) : "v"(ADDR))

__global__ __launch_bounds__(256) void k_attn(const unsigned short* __restrict__ Qp,
                                              const unsigned short* __restrict__ Kp,
                                              const unsigned short* __restrict__ Vp,
                                              unsigned short* __restrict__ part_acc,
                                              float* __restrict__ part_ml) {
    int bxr = NCHUNK - 1 - (int)blockIdx.x;   // heavy (large qt) first
    int h = blockIdx.y, b = blockIdx.z;
    int kvh = h >> 2;
    // decode bxr -> (qt, c): group g covers qt [8g,8g+8), C(qt)=g+1, base off 4g(g+1)
    int qt = 0, c = 0;
    {
        int g = (bxr >= 48) ? 3 : (bxr >= 24) ? 2 : (bxr >= 8) ? 1 : 0;
        int b0 = 4 * g * (g + 1);
        int idx = bxr - b0;
        qt = 8 * g + idx / (g + 1);
        c = idx % (g + 1);
    }
    int p = (b * NH + h) * NCHUNK + bxr;
    int qbase = qt * 64, ck0 = c * 512;
    int nt = min(8, qt + 1 - c * 8);

    int t = threadIdx.x, lane = t & 63, w = t >> 6;
    int cidx = lane & 15, quad = lane >> 4;
    int qrow0 = qbase + w * 16;

    const unsigned short* qptr  = Qp + ((size_t)(b * NH + h) * SS + qrow0) * HD;
    const unsigned short* kbase = Kp + ((size_t)(b * NKV + kvh) * SS) * HD;
    const unsigned short* vbase = Vp + (((size_t)(b * NKV + kvh) * SS) + ck0) * HD;

    __shared__ unsigned short Vt[2 * 4096];      // 2 x 8KB tiled V
    __shared__ unsigned short Pt[4][64 * 16];    // per-wave P^T [64k][16q]

    bf16x8 qa[2];
#pragma unroll
    for (int ka = 0; ka < 2; ++ka)
        qa[ka] = *reinterpret_cast<const bf16x8*>(qptr + (size_t)cidx * HD + ka * 32 + quad * 8);

    bf16x8 ones;
    {
        unsigned short ob = 0x3F80;  // bf16 1.0
        u16x8 ov;
#pragma unroll
        for (int j = 0; j < 8; ++j) ov[j] = ob;
        __builtin_memcpy(&ones, &ov, 16);
    }

    f32x4 zero = {0.f, 0.f, 0.f, 0.f};
    f32x4 acc[4], acc_l = zero;
    float m_run[4];
#pragma unroll
    for (int i = 0; i < 4; ++i) { acc[i] = zero; m_run[i] = -1e30f; }

    // V staging pattern (same verified layout as round 2)
    int e0 = t * 8, e1 = (t + 256) * 8;
    int kv0 = e0 >> 6, d00 = e0 & 63;
    int kv1 = e1 >> 6, d01 = e1 & 63;
    int woff0 = (d00 >> 4) * 1024 + (kv0 >> 2) * 64 + (kv0 & 3) * 16 + (d00 & 15);
    int woff1 = (d01 >> 4) * 1024 + (kv1 >> 2) * 64 + (kv1 & 3) * 16 + (d01 & 15);

    u16x8 vr0 = *reinterpret_cast<const u16x8*>(vbase + e0);
    u16x8 vr1 = *reinterpret_cast<const u16x8*>(vbase + e1);
    *reinterpret_cast<u16x8*>(&Vt[woff0]) = vr0;
    *reinterpret_cast<u16x8*>(&Vt[woff1]) = vr1;
    __syncthreads();

    unsigned vtb  = (unsigned)(uintptr_t)(as3_ushort*)&Vt[0];
    unsigned va_base = vtb + (unsigned)(quad * 256 + cidx * 8);
    unsigned ptb  = (unsigned)(uintptr_t)(as3_ushort*)&Pt[w][0];
    unsigned va_p = ptb + (unsigned)(quad * 256 + cidx * 8);
    char* pwr = (char*)&Pt[w][0] + cidx * 32 + quad * 8;

    for (int it = 0; it < nt; ++it) {
        int cur = it & 1;
        int kvb = ck0 + it * 64;
        if (it + 1 < nt) {
            size_t nv = (size_t)(it + 1) * 64 * HD;
            vr0 = *reinterpret_cast<const u16x8*>(vbase + nv + e0);
            vr1 = *reinterpret_cast<const u16x8*>(vbase + nv + e1);
        }

        // ---- QK^T ----
        f32x4 sc[4];
#pragma unroll
        for (int ht = 0; ht < 4; ++ht) {
            f32x4 cacc = zero;
#pragma unroll
            for (int ka = 0; ka < 2; ++ka) {
                bf16x8 kb = *reinterpret_cast<const bf16x8*>(
                    kbase + (size_t)(kvb + ht * 16 + cidx) * HD + ka * 32 + quad * 8);
                cacc = __builtin_amdgcn_mfma_f32_16x16x32_bf16(qa[ka], kb, cacc, 0, 0, 0);
            }
            sc[ht] = cacc;
        }

        // ---- causal mask (diagonal tile only; Q pre-scaled by 1/8) ----
        if (kvb + 63 > qrow0) {
#pragma unroll
            for (int ht = 0; ht < 4; ++ht)
#pragma unroll
                for (int i = 0; i < 4; ++i)
                    if (kvb + ht * 16 + cidx > qrow0 + quad * 4 + i) sc[ht][i] = -1e30f;
        }

        // ---- row max (over 16 cidx lanes) ----
        float mx[4];
#pragma unroll
        for (int i = 0; i < 4; ++i)
            mx[i] = fmaxf(fmaxf(sc[0][i], sc[1][i]), fmaxf(sc[2][i], sc[3][i]));
#pragma unroll
        for (int d = 1; d < 16; d <<= 1)
#pragma unroll
            for (int i = 0; i < 4; ++i) mx[i] = fmaxf(mx[i], __shfl_xor(mx[i], d, 64));

        // ---- online softmax (l via ones-MFMA below) ----
        float scl[4];
#pragma unroll
        for (int i = 0; i < 4; ++i) {
            float mnew = fmaxf(m_run[i], mx[i]);
            scl[i] = __expf(m_run[i] - mnew);
            m_run[i] = mnew;
#pragma unroll
            for (int ht = 0; ht < 4; ++ht) sc[ht][i] = __expf(sc[ht][i] - mnew);
        }

        // ---- P^T -> LDS: pack pairs with cvt_pk, 4x ds_write_b64 ----
#pragma unroll
        for (int ht = 0; ht < 4; ++ht) {
            u32x2 pk;
            pk[0] = cvt_pk_bf16(sc[ht][0], sc[ht][1]);
            pk[1] = cvt_pk_bf16(sc[ht][2], sc[ht][3]);
            *reinterpret_cast<u32x2*>(pwr + ht * 512) = pk;
        }
        asm volatile("" ::: "memory");

        // ---- rescale accumulators ----
#pragma unroll
        for (int dt = 0; dt < 4; ++dt)
#pragma unroll
            for (int i = 0; i < 4; ++i) acc[dt][i] *= scl[i];
#pragma unroll
        for (int i = 0; i < 4; ++i) acc_l[i] *= scl[i];

        // ---- tr-reads: P (4) + V (16) ----
        u32x2 ptr_[2][2];
        TRR(ptr_[0][0], va_p, 0);    TRR(ptr_[0][1], va_p, 128);
        TRR(ptr_[1][0], va_p, 1024); TRR(ptr_[1][1], va_p, 1152);
        unsigned va = va_base + (unsigned)(cur * 8192);
        u32x2 tr[4][2][2];
        TRR(tr[0][0][0], va, 0);    TRR(tr[0][0][1], va, 128);
        TRR(tr[0][1][0], va, 1024); TRR(tr[0][1][1], va, 1152);
        TRR(tr[1][0][0], va, 2048); TRR(tr[1][0][1], va, 2176);
        TRR(tr[1][1][0], va, 3072); TRR(tr[1][1][1], va, 3200);
        TRR(tr[2][0][0], va, 4096); TRR(tr[2][0][1], va, 4224);
        TRR(tr[2][1][0], va, 5120); TRR(tr[2][1][1], va, 5248);
        TRR(tr[3][0][0], va, 6144); TRR(tr[3][0][1], va, 6272);
        TRR(tr[3][1][0], va, 7168); TRR(tr[3][1][1], va, 7296);
        asm volatile("s_waitcnt lgkmcnt(0)" ::: "memory");
        __builtin_amdgcn_sched_barrier(0);

        union { u32x2 a[2]; bf16x8 v; } up0, up1;
        up0.a[0] = ptr_[0][0]; up0.a[1] = ptr_[0][1];
        up1.a[0] = ptr_[1][0]; up1.a[1] = ptr_[1][1];
        bf16x8 pa0 = up0.v, pa1 = up1.v;

        // l rowsum via ones-B MFMA
        acc_l = __builtin_amdgcn_mfma_f32_16x16x32_bf16(pa0, ones, acc_l, 0, 0, 0);
        acc_l = __builtin_amdgcn_mfma_f32_16x16x32_bf16(pa1, ones, acc_l, 0, 0, 0);

#pragma unroll
        for (int dt = 0; dt < 4; ++dt) {
            union { u32x2 a[2]; bf16x8 v; } u0, u1;
            u0.a[0] = tr[dt][0][0]; u0.a[1] = tr[dt][0][1];
            u1.a[0] = tr[dt][1][0]; u1.a[1] = tr[dt][1][1];
            acc[dt] = __builtin_amdgcn_mfma_f32_16x16x32_bf16(pa0, u0.v, acc[dt], 0, 0, 0);
            acc[dt] = __builtin_amdgcn_mfma_f32_16x16x32_bf16(pa1, u1.v, acc[dt], 0, 0, 0);
        }

        if (it + 1 < nt) {
            *reinterpret_cast<u16x8*>(&Vt[(cur ^ 1) * 4096 + woff0]) = vr0;
            *reinterpret_cast<u16x8*>(&Vt[(cur ^ 1) * 4096 + woff1]) = vr1;
        }
        __syncthreads();
    }

    // ---- partial epilogue (unnormalized) ----
#pragma unroll
    for (int dt = 0; dt < 4; ++dt)
#pragma unroll
        for (int i = 0; i < 4; ++i) {
            int row = w * 16 + quad * 4 + i;
            part_acc[((size_t)p * 64 + row) * 64 + dt * 16 + cidx] = f2bf(acc[dt][i]);
        }
    if (cidx == 0) {
#pragma unroll
        for (int i = 0; i < 4; ++i) {
            int row = w * 16 + quad * 4 + i;
            part_ml[((size_t)p * 64 + row) * 2 + 0] = m_run[i];
            part_ml[((size_t)p * 64 + row) * 2 + 1] = acc_l[i];
        }
    }
}

// ---------- combine partials -> attention output [B*S][HIDN] bf16 ----------
__global__ __launch_bounds__(256) void k_combine(const unsigned short* __restrict__ part_acc,
                                                 const float* __restrict__ part_ml,
                                                 unsigned short* __restrict__ a_out) {
    int idx = blockIdx.x * 256 + threadIdx.x;  // MTOT*NH*HD
    int d = idx & 63;
    int tmp = idx >> 6;
    int h = tmp % NH;
    int m_ = tmp / NH;           // b*SS + s
    int s = m_ & 2047;
    int qt = s >> 6, row = s & 63;
    int g = qt >> 3, r = qt & 7;
    int off = 4 * g * (g + 1) + r * (g + 1);
    int C = g + 1;
    int pb = ((m_ >> 11) * NH + h) * NCHUNK + off;

    float2 ml[4];
    float M = -1e30f;
#pragma unroll
    for (int cc = 0; cc < 4; ++cc) {
        if (cc < C) {
            ml[cc] = *reinterpret_cast<const float2*>(&part_ml[((size_t)(pb + cc) * 64 + row) * 2]);
            M = fmaxf(M, ml[cc].x);
        } else {
            ml[cc] = make_float2(-1e30f, 0.f);
        }
    }
    float L = 0.f, O = 0.f;
#pragma unroll
    for (int cc = 0; cc < 4; ++cc) {
        if (cc < C) {
            float wgt = __expf(ml[cc].x - M);
            L += ml[cc].y * wgt;
            O += bf2f(part_acc[((size_t)(pb + cc) * 64 + row) * 64 + d]) * wgt;
        }
    }
    a_out[(size_t)m_ * HIDN + h * 64 + d] = f2bf(O / L);
}

extern "C" void kernel_launch(void* const* d_in, const int* in_sizes, int n_in,
                              void* d_out, int out_size, void* d_ws, size_t ws_size,
                              hipStream_t stream) {
    (void)in_sizes; (void)n_in; (void)out_size; (void)ws_size;
    const float* h_f  = (const float*)d_in[0];
    const int*   pos  = (const int*)d_in[1];
    const float* Wq_f = (const float*)d_in[2];
    const float* Wk_f = (const float*)d_in[3];
    const float* Wv_f = (const float*)d_in[4];
    const float* Wo_f = (const float*)d_in[5];
    float* out = (float*)d_out;

    char* ws = (char*)d_ws;
    size_t off = 0;
    auto alloc = [&](size_t bytes) -> void* {
        void* p = ws + off;
        off += (bytes + 255) & ~(size_t)255;
        return p;
    };
    // region 0: h_bf + qkv_rm, later reused as part_acc (dead after pack kernels)
    unsigned short* h_bf   = (unsigned short*)alloc((size_t)MTOT * HIDN * 2);      // 12.58MB
    unsigned short* qkv_rm = (unsigned short*)alloc((size_t)MTOT * NQKV * 2);      // 18.87MB
    unsigned short* part_acc = h_bf;   // 48*80 * 64*64 * 2B = 31.46MB, fits exactly
    unsigned short* qkv_w  = (unsigned short*)alloc((size_t)NQKV * HIDN * 2);
    unsigned short* Wo_bf  = (unsigned short*)alloc((size_t)HIDN * NH * HD * 2);
    unsigned short* q_p    = (unsigned short*)alloc((size_t)MTOT * NH * HD * 2);
    unsigned short* k_p    = (unsigned short*)alloc((size_t)MTOT * NKV * HD * 2);
    unsigned short* v_p    = (unsigned short*)alloc((size_t)MTOT * NKV * HD * 2);
    unsigned short* a_out  = (unsigned short*)alloc((size_t)MTOT * HIDN * 2);
    float* cosT = (float*)alloc((size_t)SS * 32 * 4);
    float* sinT = (float*)alloc((size_t)SS * 32 * 4);
    float* part_ml = (float*)alloc((size_t)BB * NH * NCHUNK * 64 * 2 * 4);

    k_cast<<<(MTOT * HIDN / 4 + 255) / 256, 256, 0, stream>>>(h_f, h_bf, MTOT * HIDN / 4);
    k_cast<<<(HIDN * HIDN / 4 + 255) / 256, 256, 0, stream>>>(Wq_f, qkv_w, HIDN * HIDN / 4);
    k_cast<<<(NKV * HD * HIDN / 4 + 255) / 256, 256, 0, stream>>>(
        Wk_f, qkv_w + (size_t)HIDN * HIDN, NKV * HD * HIDN / 4);
    k_cast<<<(NKV * HD * HIDN / 4 + 255) / 256, 256, 0, stream>>>(
        Wv_f, qkv_w + (size_t)(HIDN + NKV * HD) * HIDN, NKV * HD * HIDN / 4);
    k_cast<<<(HIDN * NH * HD / 4 + 255) / 256, 256, 0, stream>>>(Wo_f, Wo_bf, HIDN * NH * HD / 4);
    k_rope_table<<<(SS * 32 + 255) / 256, 256, 0, stream>>>(cosT, sinT);

    // fused QKV projection
    gemm_bt<unsigned short><<<dim3(NQKV / 128, MTOT / 128), 256, 0, stream>>>(
        h_bf, qkv_w, qkv_rm, NQKV, HIDN);

    k_rope_pack<<<(MTOT * NH * 32) / 256, 256, 0, stream>>>(
        qkv_rm, NQKV, 0, pos, cosT, sinT, q_p, NH, 0.125f);   // Q pre-scaled by 1/sqrt(64)
    k_rope_pack<<<(MTOT * NKV * 32) / 256, 256, 0, stream>>>(
        qkv_rm, NQKV, NH * HD, pos, cosT, sinT, k_p, NKV, 1.0f);
    k_pack_v<<<(MTOT * NKV * HD) / 256, 256, 0, stream>>>(
        qkv_rm, NQKV, NH * HD + NKV * HD, v_p);

    // split-KV attention + combine (part_acc overlays the now-dead h_bf/qkv_rm region)
    k_attn<<<dim3(NCHUNK, NH, BB), 256, 0, stream>>>(q_p, k_p, v_p, part_acc, part_ml);
    k_combine<<<(MTOT * NH * HD) / 256, 256, 0, stream>>>(part_acc, part_ml, a_out);

    gemm_bt<float><<<dim3(HIDN / 128, MTOT / 128), 256, 0, stream>>>(
        a_out, Wo_bf, out, HIDN, HIDN);
}

// Round 4
// 297.215 us; speedup vs baseline: 1.4263x; 1.0093x over previous
//
#include <hip/hip_runtime.h>
#include <hip/hip_bf16.h>

// ---- problem constants ----
#define HIDN 1536
#define NH   24
#define NKV  6
#define HD   64
#define BB   2
#define SS   2048
#define MTOT (BB*SS)   // 4096
#define NQKV 2304      // NH*HD + 2*NKV*HD
#define NCHUNK 80      // sum over qt=0..31 of (qt/8+1)

typedef __bf16 bf16x8 __attribute__((ext_vector_type(8)));
typedef float  f32x4  __attribute__((ext_vector_type(4)));
typedef unsigned short u16x8 __attribute__((ext_vector_type(8)));
typedef unsigned int   u32x2 __attribute__((ext_vector_type(2)));

typedef __attribute__((address_space(1))) const unsigned short as1_ushort;
typedef __attribute__((address_space(3))) unsigned short as3_ushort;

__device__ inline float bf2f(unsigned short u) {
    unsigned v = (unsigned)u << 16; float f; __builtin_memcpy(&f, &v, 4); return f;
}
__device__ inline unsigned short f2bf(float f) {
    unsigned u; __builtin_memcpy(&u, &f, 4);
    u = (u + 0x7FFFu + ((u >> 16) & 1u)) >> 16;
    return (unsigned short)u;
}
__device__ inline unsigned cvt_pk_bf16(float lo, float hi) {
    unsigned r;
    asm("v_cvt_pk_bf16_f32 %0, %1, %2" : "=v"(r) : "v"(lo), "v"(hi));
    return r;
}
__device__ inline void store_out(float* p, float v) { *p = v; }
__device__ inline void store_out(unsigned short* p, float v) { *p = f2bf(v); }

// ---------- cast f32 -> bf16, 4 elems/thread ----------
__global__ __launch_bounds__(256) void k_cast(const float* __restrict__ in,
                                              unsigned short* __restrict__ out, int n4) {
    int i = blockIdx.x * 256 + threadIdx.x;
    if (i >= n4) return;
    float4 v = reinterpret_cast<const float4*>(in)[i];
    ushort4 o;
    o.x = f2bf(v.x); o.y = f2bf(v.y); o.z = f2bf(v.z); o.w = f2bf(v.w);
    reinterpret_cast<ushort4*>(out)[i] = o;
}

// ---------- RoPE cos/sin table: [S][32] each ----------
__global__ __launch_bounds__(256) void k_rope_table(float* __restrict__ cosT,
                                                    float* __restrict__ sinT) {
    int i = blockIdx.x * 256 + threadIdx.x;
    if (i >= SS * 32) return;
    int s = i >> 5, f = i & 31;
    double inv = pow(10000.0, -(double)f / 32.0);
    double ang = (double)s * inv;
    cosT[i] = (float)cos(ang);
    sinT[i] = (float)sin(ang);
}

// ---------- GEMM (m97 structure): C[M,N] = A[M,K](bf16) @ Bt[N,K](bf16)^T ----------
template <typename OutT>
__global__ __launch_bounds__(256) void gemm_bt(const unsigned short* __restrict__ A,
                                               const unsigned short* __restrict__ Bt,
                                               OutT* __restrict__ C,
                                               int N, int K) {
    __shared__ unsigned short Alds[128 * 32];
    __shared__ unsigned short Blds[128 * 32];
    int t = threadIdx.x;
    int lane = t & 63, w = t >> 6;
    int m0 = blockIdx.y * 128, n0 = blockIdx.x * 128;
    int wm = (w >> 1) * 64, wn = (w & 1) * 64;
    int cidx = lane & 15, quad = lane >> 4;
    int srow = lane >> 2, scol = (lane & 3) * 8;

    f32x4 zero = {0.f, 0.f, 0.f, 0.f};
    f32x4 acc[4][4];
#pragma unroll
    for (int mi = 0; mi < 4; ++mi)
#pragma unroll
        for (int ni = 0; ni < 4; ++ni) acc[mi][ni] = zero;

    for (int k0 = 0; k0 < K; k0 += 32) {
        __syncthreads();
#pragma unroll
        for (int c = 0; c < 2; ++c) {
            int chunk = w + c * 4;
            int row = chunk * 16 + srow;
            __builtin_amdgcn_global_load_lds(
                (as1_ushort*)(A + (size_t)(m0 + row) * K + k0 + scol),
                (as3_ushort*)&Alds[chunk * 512], 16, 0, 0);
            __builtin_amdgcn_global_load_lds(
                (as1_ushort*)(Bt + (size_t)(n0 + row) * K + k0 + scol),
                (as3_ushort*)&Blds[chunk * 512], 16, 0, 0);
        }
        __syncthreads();
        bf16x8 af[4], bfr[4];
#pragma unroll
        for (int mi = 0; mi < 4; ++mi)
            af[mi] = *reinterpret_cast<bf16x8*>(&Alds[(wm + mi * 16 + cidx) * 32 + quad * 8]);
#pragma unroll
        for (int ni = 0; ni < 4; ++ni)
            bfr[ni] = *reinterpret_cast<bf16x8*>(&Blds[(wn + ni * 16 + cidx) * 32 + quad * 8]);
#pragma unroll
        for (int mi = 0; mi < 4; ++mi)
#pragma unroll
            for (int ni = 0; ni < 4; ++ni)
                acc[mi][ni] = __builtin_amdgcn_mfma_f32_16x16x32_bf16(af[mi], bfr[ni],
                                                                      acc[mi][ni], 0, 0, 0);
    }
#pragma unroll
    for (int mi = 0; mi < 4; ++mi)
#pragma unroll
        for (int ni = 0; ni < 4; ++ni)
#pragma unroll
            for (int i = 0; i < 4; ++i) {
                int row = m0 + wm + mi * 16 + quad * 4 + i;
                int col = n0 + wn + ni * 16 + cidx;
                store_out(&C[(size_t)row * N + col], acc[mi][ni][i]);
            }
}

// ---------- RoPE + pack to [B,H,S,HD] bf16 (with optional pre-scale) ----------
__global__ __launch_bounds__(256) void k_rope_pack(const unsigned short* __restrict__ in,
                                                   int istride, int col0,
                                                   const int* __restrict__ pos_ids,
                                                   const float* __restrict__ cosT,
                                                   const float* __restrict__ sinT,
                                                   unsigned short* __restrict__ out, int H,
                                                   float scale) {
    int idx = blockIdx.x * 256 + threadIdx.x;
    int total = MTOT * H * 32;
    if (idx >= total) return;
    int i = idx & 31;
    int tmp = idx >> 5;
    int h = tmp % H;
    int m = tmp / H;
    int b = m >> 11, s = m & 2047;
    int pos = pos_ids[m];
    float c = cosT[pos * 32 + i], sn = sinT[pos * 32 + i];
    float x1 = bf2f(in[(size_t)m * istride + col0 + h * HD + i]);
    float x2 = bf2f(in[(size_t)m * istride + col0 + h * HD + 32 + i]);
    size_t o = (((size_t)(b * H + h)) * SS + s) * HD + i;
    out[o]      = f2bf((x1 * c - x2 * sn) * scale);
    out[o + 32] = f2bf((x2 * c + x1 * sn) * scale);
}

__global__ __launch_bounds__(256) void k_pack_v(const unsigned short* __restrict__ in,
                                                int istride, int col0,
                                                unsigned short* __restrict__ out) {
    int idx = blockIdx.x * 256 + threadIdx.x;
    int d = idx & 63;
    int tmp = idx >> 6;
    int h = tmp % NKV;
    int m = tmp / NKV;
    int b = m >> 11, s = m & 2047;
    out[(((size_t)(b * NKV + h)) * SS + s) * HD + d] =
        in[(size_t)m * istride + col0 + h * HD + d];
}

// ---------- split-KV flash attention ----------
// grid.x = 80 chunk-blocks per (b,h): qt in [0,32), chunk c covers kv [c*512,(c+1)*512).
// 4 waves x 16 q-rows. V staged via global_load_lds (linear LDS dest, inverse-tiled
// per-lane global source). __launch_bounds__(256,4) -> <=128 regs -> 16 waves/CU.
#define TRR(dst, ADDR, OFF) asm volatile("ds_read_b64_tr_b16 %0, %1 offset:" #OFF \
                                         : "=v"(dst) : "v"(ADDR))

__global__ __launch_bounds__(256, 4) void k_attn(const unsigned short* __restrict__ Qp,
                                                 const unsigned short* __restrict__ Kp,
                                                 const unsigned short* __restrict__ Vp,
                                                 unsigned short* __restrict__ part_acc,
                                                 float* __restrict__ part_ml) {
    int bxr = NCHUNK - 1 - (int)blockIdx.x;   // heavy (large qt) first
    int h = blockIdx.y, b = blockIdx.z;
    int kvh = h >> 2;
    int qt = 0, c = 0;
    {
        int g = (bxr >= 48) ? 3 : (bxr >= 24) ? 2 : (bxr >= 8) ? 1 : 0;
        int b0 = 4 * g * (g + 1);
        int idx = bxr - b0;
        qt = 8 * g + idx / (g + 1);
        c = idx % (g + 1);
    }
    int p = (b * NH + h) * NCHUNK + bxr;
    int qbase = qt * 64, ck0 = c * 512;
    int nt = min(8, qt + 1 - c * 8);

    int t = threadIdx.x, lane = t & 63, w = t >> 6;
    int cidx = lane & 15, quad = lane >> 4;
    int qrow0 = qbase + w * 16;

    const unsigned short* qptr  = Qp + ((size_t)(b * NH + h) * SS + qrow0) * HD;
    const unsigned short* kbase = Kp + ((size_t)(b * NKV + kvh) * SS) * HD;
    const unsigned short* vbase = Vp + (((size_t)(b * NKV + kvh) * SS) + ck0) * HD;

    __shared__ unsigned short Vt[2 * 4096];      // 2 x 8KB tiled V
    __shared__ unsigned short Pt[4][64 * 16];    // per-wave P^T [64k][16q]

    // V staging: instr i of wave w writes LDS elems o = (w*2+i)*512 + lane*8 .. +8.
    // Inverse of tiled map o = (d>>4)*1024 + (kv>>2)*64 + (kv&3)*16 + (d&15):
    const unsigned short* vsrc[2];
#pragma unroll
    for (int i = 0; i < 2; ++i) {
        int o = (w * 2 + i) * 512 + lane * 8;
        int r = o & 1023;
        int kv = ((r >> 6) << 2) | ((r >> 4) & 3);
        int d  = ((o >> 10) << 4) | (r & 15);
        vsrc[i] = vbase + kv * HD + d;
    }

    bf16x8 qa[2];
#pragma unroll
    for (int ka = 0; ka < 2; ++ka)
        qa[ka] = *reinterpret_cast<const bf16x8*>(qptr + (size_t)cidx * HD + ka * 32 + quad * 8);

    bf16x8 ones;
    {
        unsigned short ob = 0x3F80;  // bf16 1.0
        u16x8 ov;
#pragma unroll
        for (int j = 0; j < 8; ++j) ov[j] = ob;
        __builtin_memcpy(&ones, &ov, 16);
    }

    f32x4 zero = {0.f, 0.f, 0.f, 0.f};
    f32x4 acc[4], acc_l = zero;
    float m_run[4];
#pragma unroll
    for (int i = 0; i < 4; ++i) { acc[i] = zero; m_run[i] = -1e30f; }

    // prologue: stage V tile 0 into buf 0
#pragma unroll
    for (int i = 0; i < 2; ++i)
        __builtin_amdgcn_global_load_lds((as1_ushort*)vsrc[i],
                                         (as3_ushort*)&Vt[(w * 2 + i) * 512], 16, 0, 0);
    asm volatile("s_waitcnt vmcnt(0)" ::: "memory");
    __syncthreads();

    unsigned vtb  = (unsigned)(uintptr_t)(as3_ushort*)&Vt[0];
    unsigned va_base = vtb + (unsigned)(quad * 256 + cidx * 8);
    unsigned ptb  = (unsigned)(uintptr_t)(as3_ushort*)&Pt[w][0];
    unsigned va_p = ptb + (unsigned)(quad * 256 + cidx * 8);
    char* pwr = (char*)&Pt[w][0] + cidx * 32 + quad * 8;

    for (int it = 0; it < nt; ++it) {
        int cur = it & 1;
        int kvb = ck0 + it * 64;

        // ---- QK^T ----
        f32x4 sc[4];
#pragma unroll
        for (int ht = 0; ht < 4; ++ht) {
            f32x4 cacc = zero;
#pragma unroll
            for (int ka = 0; ka < 2; ++ka) {
                bf16x8 kb = *reinterpret_cast<const bf16x8*>(
                    kbase + (size_t)(kvb + ht * 16 + cidx) * HD + ka * 32 + quad * 8);
                cacc = __builtin_amdgcn_mfma_f32_16x16x32_bf16(qa[ka], kb, cacc, 0, 0, 0);
            }
            sc[ht] = cacc;
        }

        // ---- issue next-tile V loads into other buffer (in flight through softmax+PV) ----
        if (it + 1 < nt) {
            size_t nv = (size_t)(it + 1) * 64 * HD;
#pragma unroll
            for (int i = 0; i < 2; ++i)
                __builtin_amdgcn_global_load_lds(
                    (as1_ushort*)(vsrc[i] + nv),
                    (as3_ushort*)&Vt[(cur ^ 1) * 4096 + (w * 2 + i) * 512], 16, 0, 0);
        }

        // ---- causal mask (diagonal tile only; Q pre-scaled by 1/8) ----
        if (kvb + 63 > qrow0) {
#pragma unroll
            for (int ht = 0; ht < 4; ++ht)
#pragma unroll
                for (int i = 0; i < 4; ++i)
                    if (kvb + ht * 16 + cidx > qrow0 + quad * 4 + i) sc[ht][i] = -1e30f;
        }

        // ---- row max (over 16 cidx lanes) ----
        float mx[4];
#pragma unroll
        for (int i = 0; i < 4; ++i)
            mx[i] = fmaxf(fmaxf(sc[0][i], sc[1][i]), fmaxf(sc[2][i], sc[3][i]));
#pragma unroll
        for (int d = 1; d < 16; d <<= 1)
#pragma unroll
            for (int i = 0; i < 4; ++i) mx[i] = fmaxf(mx[i], __shfl_xor(mx[i], d, 64));

        // ---- defer-max (T13): rescale only when max grew by > 8 ----
        bool need = false;
#pragma unroll
        for (int i = 0; i < 4; ++i) need |= (mx[i] > m_run[i] + 8.f);
        if (__any(need)) {
#pragma unroll
            for (int i = 0; i < 4; ++i) {
                float mnew = fmaxf(m_run[i], mx[i]);
                float scl = __expf(m_run[i] - mnew);
                m_run[i] = mnew;
#pragma unroll
                for (int dt = 0; dt < 4; ++dt) acc[dt][i] *= scl;
                acc_l[i] *= scl;
            }
        }
#pragma unroll
        for (int i = 0; i < 4; ++i)
#pragma unroll
            for (int ht = 0; ht < 4; ++ht) sc[ht][i] = __expf(sc[ht][i] - m_run[i]);

        // ---- P^T -> LDS: pack pairs with cvt_pk, 4x ds_write_b64 ----
#pragma unroll
        for (int ht = 0; ht < 4; ++ht) {
            u32x2 pk;
            pk[0] = cvt_pk_bf16(sc[ht][0], sc[ht][1]);
            pk[1] = cvt_pk_bf16(sc[ht][2], sc[ht][3]);
            *reinterpret_cast<u32x2*>(pwr + ht * 512) = pk;
        }
        asm volatile("" ::: "memory");

        // ---- group A: P trs + V trs (dt0,dt1) ----
        unsigned va = va_base + (unsigned)(cur * 8192);
        u32x2 pt_[4];
        TRR(pt_[0], va_p, 0);    TRR(pt_[1], va_p, 128);
        TRR(pt_[2], va_p, 1024); TRR(pt_[3], va_p, 1152);
        u32x2 tv[2][4];
        TRR(tv[0][0], va, 0);    TRR(tv[0][1], va, 128);
        TRR(tv[0][2], va, 1024); TRR(tv[0][3], va, 1152);
        TRR(tv[1][0], va, 2048); TRR(tv[1][1], va, 2176);
        TRR(tv[1][2], va, 3072); TRR(tv[1][3], va, 3200);
        asm volatile("s_waitcnt lgkmcnt(0)" ::: "memory");
        __builtin_amdgcn_sched_barrier(0);

        union { u32x2 a[2]; bf16x8 v; } up0, up1;
        up0.a[0] = pt_[0]; up0.a[1] = pt_[1];
        up1.a[0] = pt_[2]; up1.a[1] = pt_[3];
        bf16x8 pa0 = up0.v, pa1 = up1.v;

        __builtin_amdgcn_s_setprio(1);
        acc_l = __builtin_amdgcn_mfma_f32_16x16x32_bf16(pa0, ones, acc_l, 0, 0, 0);
        acc_l = __builtin_amdgcn_mfma_f32_16x16x32_bf16(pa1, ones, acc_l, 0, 0, 0);
#pragma unroll
        for (int dt = 0; dt < 2; ++dt) {
            union { u32x2 a[2]; bf16x8 v; } u0, u1;
            u0.a[0] = tv[dt][0]; u0.a[1] = tv[dt][1];
            u1.a[0] = tv[dt][2]; u1.a[1] = tv[dt][3];
            acc[dt] = __builtin_amdgcn_mfma_f32_16x16x32_bf16(pa0, u0.v, acc[dt], 0, 0, 0);
            acc[dt] = __builtin_amdgcn_mfma_f32_16x16x32_bf16(pa1, u1.v, acc[dt], 0, 0, 0);
        }
        __builtin_amdgcn_s_setprio(0);

        // ---- group B: V trs (dt2,dt3) ----
        u32x2 tw[2][4];
        TRR(tw[0][0], va, 4096); TRR(tw[0][1], va, 4224);
        TRR(tw[0][2], va, 5120); TRR(tw[0][3], va, 5248);
        TRR(tw[1][0], va, 6144); TRR(tw[1][1], va, 6272);
        TRR(tw[1][2], va, 7168); TRR(tw[1][3], va, 7296);
        asm volatile("s_waitcnt lgkmcnt(0)" ::: "memory");
        __builtin_amdgcn_sched_barrier(0);

        __builtin_amdgcn_s_setprio(1);
#pragma unroll
        for (int dt = 0; dt < 2; ++dt) {
            union { u32x2 a[2]; bf16x8 v; } u0, u1;
            u0.a[0] = tw[dt][0]; u0.a[1] = tw[dt][1];
            u1.a[0] = tw[dt][2]; u1.a[1] = tw[dt][3];
            acc[dt + 2] = __builtin_amdgcn_mfma_f32_16x16x32_bf16(pa0, u0.v, acc[dt + 2], 0, 0, 0);
            acc[dt + 2] = __builtin_amdgcn_mfma_f32_16x16x32_bf16(pa1, u1.v, acc[dt + 2], 0, 0, 0);
        }
        __builtin_amdgcn_s_setprio(0);

        // next-tile V loads have had softmax+PV to land; drain + sync
        asm volatile("s_waitcnt vmcnt(0)" ::: "memory");
        __syncthreads();
    }

    // ---- partial epilogue (unnormalized; m_run may be stale per defer-max, l consistent) ----
#pragma unroll
    for (int dt = 0; dt < 4; ++dt)
#pragma unroll
        for (int i = 0; i < 4; ++i) {
            int row = w * 16 + quad * 4 + i;
            part_acc[((size_t)p * 64 + row) * 64 + dt * 16 + cidx] = f2bf(acc[dt][i]);
        }
    if (cidx == 0) {
#pragma unroll
        for (int i = 0; i < 4; ++i) {
            int row = w * 16 + quad * 4 + i;
            part_ml[((size_t)p * 64 + row) * 2 + 0] = m_run[i];
            part_ml[((size_t)p * 64 + row) * 2 + 1] = acc_l[i];
        }
    }
}

// ---------- combine partials -> attention output [B*S][HIDN] bf16 ----------
__global__ __launch_bounds__(256) void k_combine(const unsigned short* __restrict__ part_acc,
                                                 const float* __restrict__ part_ml,
                                                 unsigned short* __restrict__ a_out) {
    int idx = blockIdx.x * 256 + threadIdx.x;  // MTOT*NH*HD
    int d = idx & 63;
    int tmp = idx >> 6;
    int h = tmp % NH;
    int m_ = tmp / NH;           // b*SS + s
    int s = m_ & 2047;
    int qt = s >> 6, row = s & 63;
    int g = qt >> 3, r = qt & 7;
    int off = 4 * g * (g + 1) + r * (g + 1);
    int C = g + 1;
    int pb = ((m_ >> 11) * NH + h) * NCHUNK + off;

    float2 ml[4];
    float M = -1e30f;
#pragma unroll
    for (int cc = 0; cc < 4; ++cc) {
        if (cc < C) {
            ml[cc] = *reinterpret_cast<const float2*>(&part_ml[((size_t)(pb + cc) * 64 + row) * 2]);
            M = fmaxf(M, ml[cc].x);
        } else {
            ml[cc] = make_float2(-1e30f, 0.f);
        }
    }
    float L = 0.f, O = 0.f;
#pragma unroll
    for (int cc = 0; cc < 4; ++cc) {
        if (cc < C) {
            float wgt = __expf(ml[cc].x - M);
            L += ml[cc].y * wgt;
            O += bf2f(part_acc[((size_t)(pb + cc) * 64 + row) * 64 + d]) * wgt;
        }
    }
    a_out[(size_t)m_ * HIDN + h * 64 + d] = f2bf(O / L);
}

extern "C" void kernel_launch(void* const* d_in, const int* in_sizes, int n_in,
                              void* d_out, int out_size, void* d_ws, size_t ws_size,
                              hipStream_t stream) {
    (void)in_sizes; (void)n_in; (void)out_size; (void)ws_size;
    const float* h_f  = (const float*)d_in[0];
    const int*   pos  = (const int*)d_in[1];
    const float* Wq_f = (const float*)d_in[2];
    const float* Wk_f = (const float*)d_in[3];
    const float* Wv_f = (const float*)d_in[4];
    const float* Wo_f = (const float*)d_in[5];
    float* out = (float*)d_out;

    char* ws = (char*)d_ws;
    size_t off = 0;
    auto alloc = [&](size_t bytes) -> void* {
        void* p = ws + off;
        off += (bytes + 255) & ~(size_t)255;
        return p;
    };
    // region 0: h_bf + qkv_rm, later reused as part_acc (dead after pack kernels)
    unsigned short* h_bf   = (unsigned short*)alloc((size_t)MTOT * HIDN * 2);      // 12.58MB
    unsigned short* qkv_rm = (unsigned short*)alloc((size_t)MTOT * NQKV * 2);      // 18.87MB
    unsigned short* part_acc = h_bf;   // 48*80 * 64*64 * 2B = 31.46MB, fits exactly
    unsigned short* qkv_w  = (unsigned short*)alloc((size_t)NQKV * HIDN * 2);
    unsigned short* Wo_bf  = (unsigned short*)alloc((size_t)HIDN * NH * HD * 2);
    unsigned short* q_p    = (unsigned short*)alloc((size_t)MTOT * NH * HD * 2);
    unsigned short* k_p    = (unsigned short*)alloc((size_t)MTOT * NKV * HD * 2);
    unsigned short* v_p    = (unsigned short*)alloc((size_t)MTOT * NKV * HD * 2);
    unsigned short* a_out  = (unsigned short*)alloc((size_t)MTOT * HIDN * 2);
    float* cosT = (float*)alloc((size_t)SS * 32 * 4);
    float* sinT = (float*)alloc((size_t)SS * 32 * 4);
    float* part_ml = (float*)alloc((size_t)BB * NH * NCHUNK * 64 * 2 * 4);

    k_cast<<<(MTOT * HIDN / 4 + 255) / 256, 256, 0, stream>>>(h_f, h_bf, MTOT * HIDN / 4);
    k_cast<<<(HIDN * HIDN / 4 + 255) / 256, 256, 0, stream>>>(Wq_f, qkv_w, HIDN * HIDN / 4);
    k_cast<<<(NKV * HD * HIDN / 4 + 255) / 256, 256, 0, stream>>>(
        Wk_f, qkv_w + (size_t)HIDN * HIDN, NKV * HD * HIDN / 4);
    k_cast<<<(NKV * HD * HIDN / 4 + 255) / 256, 256, 0, stream>>>(
        Wv_f, qkv_w + (size_t)(HIDN + NKV * HD) * HIDN, NKV * HD * HIDN / 4);
    k_cast<<<(HIDN * NH * HD / 4 + 255) / 256, 256, 0, stream>>>(Wo_f, Wo_bf, HIDN * NH * HD / 4);
    k_rope_table<<<(SS * 32 + 255) / 256, 256, 0, stream>>>(cosT, sinT);

    // fused QKV projection
    gemm_bt<unsigned short><<<dim3(NQKV / 128, MTOT / 128), 256, 0, stream>>>(
        h_bf, qkv_w, qkv_rm, NQKV, HIDN);

    k_rope_pack<<<(MTOT * NH * 32) / 256, 256, 0, stream>>>(
        qkv_rm, NQKV, 0, pos, cosT, sinT, q_p, NH, 0.125f);   // Q pre-scaled by 1/sqrt(64)
    k_rope_pack<<<(MTOT * NKV * 32) / 256, 256, 0, stream>>>(
        qkv_rm, NQKV, NH * HD, pos, cosT, sinT, k_p, NKV, 1.0f);
    k_pack_v<<<(MTOT * NKV * HD) / 256, 256, 0, stream>>>(
        qkv_rm, NQKV, NH * HD + NKV * HD, v_p);

    // split-KV attention + combine (part_acc overlays the now-dead h_bf/qkv_rm region)
    k_attn<<<dim3(NCHUNK, NH, BB), 256, 0, stream>>>(q_p, k_p, v_p, part_acc, part_ml);
    k_combine<<<(MTOT * NH * HD) / 256, 256, 0, stream>>>(part_acc, part_ml, a_out);

    gemm_bt<float><<<dim3(HIDN / 128, MTOT / 128), 256, 0, stream>>>(
        a_out, Wo_bf, out, HIDN, HIDN);
}

// Round 5
// 237.596 us; speedup vs baseline: 1.7842x; 1.2509x over previous
//
#include <hip/hip_runtime.h>
#include <hip/hip_bf16.h>

// ---- problem constants ----
#define HIDN 1536
#define NH   24
#define NKV  6
#define HD   64
#define BB   2
#define SS   2048
#define MTOT (BB*SS)   // 4096
#define NQKV 2304      // NH*HD + 2*NKV*HD
#define NCHUNK 80      // sum over qt=0..31 of (qt/8+1)

typedef __bf16 bf16x8 __attribute__((ext_vector_type(8)));
typedef float  f32x4  __attribute__((ext_vector_type(4)));
typedef unsigned short u16x8 __attribute__((ext_vector_type(8)));
typedef unsigned int   u32x2 __attribute__((ext_vector_type(2)));

typedef __attribute__((address_space(1))) const unsigned short as1_ushort;
typedef __attribute__((address_space(3))) unsigned short as3_ushort;

__device__ inline float bf2f(unsigned short u) {
    unsigned v = (unsigned)u << 16; float f; __builtin_memcpy(&f, &v, 4); return f;
}
__device__ inline unsigned short f2bf(float f) {
    unsigned u; __builtin_memcpy(&u, &f, 4);
    u = (u + 0x7FFFu + ((u >> 16) & 1u)) >> 16;
    return (unsigned short)u;
}
__device__ inline unsigned cvt_pk_bf16(float lo, float hi) {
    unsigned r;
    asm("v_cvt_pk_bf16_f32 %0, %1, %2" : "=v"(r) : "v"(lo), "v"(hi));
    return r;
}
// all-reduce max within each 16-lane DPP row via row_ror rotations (VALU-speed)
__device__ inline float rowmax16_dpp(float x) {
    int v, r;
    v = __float_as_int(x);
    r = __builtin_amdgcn_update_dpp(v, v, 0x121, 0xF, 0xF, false);  // row_ror:1
    x = fmaxf(x, __int_as_float(r));
    v = __float_as_int(x);
    r = __builtin_amdgcn_update_dpp(v, v, 0x122, 0xF, 0xF, false);  // row_ror:2
    x = fmaxf(x, __int_as_float(r));
    v = __float_as_int(x);
    r = __builtin_amdgcn_update_dpp(v, v, 0x124, 0xF, 0xF, false);  // row_ror:4
    x = fmaxf(x, __int_as_float(r));
    v = __float_as_int(x);
    r = __builtin_amdgcn_update_dpp(v, v, 0x128, 0xF, 0xF, false);  // row_ror:8
    x = fmaxf(x, __int_as_float(r));
    return x;
}
__device__ inline void store_out(float* p, float v) { *p = v; }
__device__ inline void store_out(unsigned short* p, float v) { *p = f2bf(v); }

// ---------- cast f32 -> bf16, 4 elems/thread ----------
__global__ __launch_bounds__(256) void k_cast(const float* __restrict__ in,
                                              unsigned short* __restrict__ out, int n4) {
    int i = blockIdx.x * 256 + threadIdx.x;
    if (i >= n4) return;
    float4 v = reinterpret_cast<const float4*>(in)[i];
    ushort4 o;
    o.x = f2bf(v.x); o.y = f2bf(v.y); o.z = f2bf(v.z); o.w = f2bf(v.w);
    reinterpret_cast<ushort4*>(out)[i] = o;
}

// ---------- RoPE cos/sin table: [S][32] each ----------
__global__ __launch_bounds__(256) void k_rope_table(float* __restrict__ cosT,
                                                    float* __restrict__ sinT) {
    int i = blockIdx.x * 256 + threadIdx.x;
    if (i >= SS * 32) return;
    int s = i >> 5, f = i & 31;
    double inv = pow(10000.0, -(double)f / 32.0);
    double ang = (double)s * inv;
    cosT[i] = (float)cos(ang);
    sinT[i] = (float)sin(ang);
}

// ---------- GEMM (m97 structure): C[M,N] = A[M,K](bf16) @ Bt[N,K](bf16)^T ----------
template <typename OutT>
__global__ __launch_bounds__(256) void gemm_bt(const unsigned short* __restrict__ A,
                                               const unsigned short* __restrict__ Bt,
                                               OutT* __restrict__ C,
                                               int N, int K) {
    __shared__ unsigned short Alds[128 * 32];
    __shared__ unsigned short Blds[128 * 32];
    int t = threadIdx.x;
    int lane = t & 63, w = t >> 6;
    int m0 = blockIdx.y * 128, n0 = blockIdx.x * 128;
    int wm = (w >> 1) * 64, wn = (w & 1) * 64;
    int cidx = lane & 15, quad = lane >> 4;
    int srow = lane >> 2, scol = (lane & 3) * 8;

    f32x4 zero = {0.f, 0.f, 0.f, 0.f};
    f32x4 acc[4][4];
#pragma unroll
    for (int mi = 0; mi < 4; ++mi)
#pragma unroll
        for (int ni = 0; ni < 4; ++ni) acc[mi][ni] = zero;

    for (int k0 = 0; k0 < K; k0 += 32) {
        __syncthreads();
#pragma unroll
        for (int c = 0; c < 2; ++c) {
            int chunk = w + c * 4;
            int row = chunk * 16 + srow;
            __builtin_amdgcn_global_load_lds(
                (as1_ushort*)(A + (size_t)(m0 + row) * K + k0 + scol),
                (as3_ushort*)&Alds[chunk * 512], 16, 0, 0);
            __builtin_amdgcn_global_load_lds(
                (as1_ushort*)(Bt + (size_t)(n0 + row) * K + k0 + scol),
                (as3_ushort*)&Blds[chunk * 512], 16, 0, 0);
        }
        __syncthreads();
        bf16x8 af[4], bfr[4];
#pragma unroll
        for (int mi = 0; mi < 4; ++mi)
            af[mi] = *reinterpret_cast<bf16x8*>(&Alds[(wm + mi * 16 + cidx) * 32 + quad * 8]);
#pragma unroll
        for (int ni = 0; ni < 4; ++ni)
            bfr[ni] = *reinterpret_cast<bf16x8*>(&Blds[(wn + ni * 16 + cidx) * 32 + quad * 8]);
#pragma unroll
        for (int mi = 0; mi < 4; ++mi)
#pragma unroll
            for (int ni = 0; ni < 4; ++ni)
                acc[mi][ni] = __builtin_amdgcn_mfma_f32_16x16x32_bf16(af[mi], bfr[ni],
                                                                      acc[mi][ni], 0, 0, 0);
    }
#pragma unroll
    for (int mi = 0; mi < 4; ++mi)
#pragma unroll
        for (int ni = 0; ni < 4; ++ni)
#pragma unroll
            for (int i = 0; i < 4; ++i) {
                int row = m0 + wm + mi * 16 + quad * 4 + i;
                int col = n0 + wn + ni * 16 + cidx;
                store_out(&C[(size_t)row * N + col], acc[mi][ni][i]);
            }
}

// ---------- RoPE + pack to [B,H,S,HD] bf16 (with optional pre-scale) ----------
__global__ __launch_bounds__(256) void k_rope_pack(const unsigned short* __restrict__ in,
                                                   int istride, int col0,
                                                   const int* __restrict__ pos_ids,
                                                   const float* __restrict__ cosT,
                                                   const float* __restrict__ sinT,
                                                   unsigned short* __restrict__ out, int H,
                                                   float scale) {
    int idx = blockIdx.x * 256 + threadIdx.x;
    int total = MTOT * H * 32;
    if (idx >= total) return;
    int i = idx & 31;
    int tmp = idx >> 5;
    int h = tmp % H;
    int m = tmp / H;
    int b = m >> 11, s = m & 2047;
    int pos = pos_ids[m];
    float c = cosT[pos * 32 + i], sn = sinT[pos * 32 + i];
    float x1 = bf2f(in[(size_t)m * istride + col0 + h * HD + i]);
    float x2 = bf2f(in[(size_t)m * istride + col0 + h * HD + 32 + i]);
    size_t o = (((size_t)(b * H + h)) * SS + s) * HD + i;
    out[o]      = f2bf((x1 * c - x2 * sn) * scale);
    out[o + 32] = f2bf((x2 * c + x1 * sn) * scale);
}

__global__ __launch_bounds__(256) void k_pack_v(const unsigned short* __restrict__ in,
                                                int istride, int col0,
                                                unsigned short* __restrict__ out) {
    int idx = blockIdx.x * 256 + threadIdx.x;
    int d = idx & 63;
    int tmp = idx >> 6;
    int h = tmp % NKV;
    int m = tmp / NKV;
    int b = m >> 11, s = m & 2047;
    out[(((size_t)(b * NKV + h)) * SS + s) * HD + d] =
        in[(size_t)m * istride + col0 + h * HD + d];
}

// ---------- split-KV flash attention ----------
// grid.x = 80 chunk-blocks per (b,h): qt in [0,32), chunk c covers kv [c*512,(c+1)*512).
// 4 waves x 16 q-rows. K AND V staged via global_load_lds (linear LDS dest,
// inverse-tiled per-lane global source), double-buffered, prefetch 1 tile ahead.
// Row-max reduce via DPP row_ror (VALU) instead of shfl_xor (DS).
#define TRR(dst, ADDR, OFF) asm volatile("ds_read_b64_tr_b16 %0, %1 offset:" #OFF \
                                         : "=v"(dst) : "v"(ADDR))

__global__ __launch_bounds__(256, 4) void k_attn(const unsigned short* __restrict__ Qp,
                                                 const unsigned short* __restrict__ Kp,
                                                 const unsigned short* __restrict__ Vp,
                                                 unsigned short* __restrict__ part_acc,
                                                 float* __restrict__ part_ml) {
    int bxr = NCHUNK - 1 - (int)blockIdx.x;   // heavy (large qt) first
    int h = blockIdx.y, b = blockIdx.z;
    int kvh = h >> 2;
    int qt = 0, c = 0;
    {
        int g = (bxr >= 48) ? 3 : (bxr >= 24) ? 2 : (bxr >= 8) ? 1 : 0;
        int b0 = 4 * g * (g + 1);
        int idx = bxr - b0;
        qt = 8 * g + idx / (g + 1);
        c = idx % (g + 1);
    }
    int p = (b * NH + h) * NCHUNK + bxr;
    int qbase = qt * 64, ck0 = c * 512;
    int nt = min(8, qt + 1 - c * 8);

    int t = threadIdx.x, lane = t & 63, w = t >> 6;
    int cidx = lane & 15, quad = lane >> 4;
    int qrow0 = qbase + w * 16;

    const unsigned short* qptr  = Qp + ((size_t)(b * NH + h) * SS + qrow0) * HD;
    const unsigned short* kbase = Kp + (((size_t)(b * NKV + kvh) * SS) + ck0) * HD;
    const unsigned short* vbase = Vp + (((size_t)(b * NKV + kvh) * SS) + ck0) * HD;

    __shared__ unsigned short Klds[2 * 4096];    // 2 x 8KB tiled K [ht][ka][quad][cidx][8]
    __shared__ unsigned short Vt[2 * 4096];      // 2 x 8KB tiled V [d16][kv4][4][16]
    __shared__ unsigned short Pt[4][64 * 16];    // per-wave P^T

    // staging source permutations: chunk ci=w*2+i covers LDS elems [ci*512, ci*512+512)
    const unsigned short* ksrc[2];
    const unsigned short* vsrc[2];
#pragma unroll
    for (int i = 0; i < 2; ++i) {
        int o = (w * 2 + i) * 512 + lane * 8;
        // K tiled layout: o = ht*1024 + ka*512 + quad*128 + cidx*8
        int kh = o >> 10, ka = (o >> 9) & 1, kq = (o >> 7) & 3, kc = (o >> 3) & 15;
        ksrc[i] = kbase + (kh * 16 + kc) * HD + ka * 32 + kq * 8;
        // V tiled layout: o = (d>>4)*1024 + (kv>>2)*64 + (kv&3)*16 + (d&15)
        int r = o & 1023;
        int kv = ((r >> 6) << 2) | ((r >> 4) & 3);
        int d  = ((o >> 10) << 4) | (r & 15);
        vsrc[i] = vbase + kv * HD + d;
    }

    bf16x8 qa[2];
#pragma unroll
    for (int ka = 0; ka < 2; ++ka)
        qa[ka] = *reinterpret_cast<const bf16x8*>(qptr + (size_t)cidx * HD + ka * 32 + quad * 8);

    bf16x8 ones;
    {
        unsigned short ob = 0x3F80;  // bf16 1.0
        u16x8 ov;
#pragma unroll
        for (int j = 0; j < 8; ++j) ov[j] = ob;
        __builtin_memcpy(&ones, &ov, 16);
    }

    f32x4 zero = {0.f, 0.f, 0.f, 0.f};
    f32x4 acc[4], acc_l = zero;
    float m_run[4];
#pragma unroll
    for (int i = 0; i < 4; ++i) { acc[i] = zero; m_run[i] = -1e30f; }

    // prologue: stage K0,V0 into buf 0
#pragma unroll
    for (int i = 0; i < 2; ++i) {
        __builtin_amdgcn_global_load_lds((as1_ushort*)ksrc[i],
                                         (as3_ushort*)&Klds[(w * 2 + i) * 512], 16, 0, 0);
        __builtin_amdgcn_global_load_lds((as1_ushort*)vsrc[i],
                                         (as3_ushort*)&Vt[(w * 2 + i) * 512], 16, 0, 0);
    }
    asm volatile("s_waitcnt vmcnt(0)" ::: "memory");
    __syncthreads();

    unsigned vtb  = (unsigned)(uintptr_t)(as3_ushort*)&Vt[0];
    unsigned va_base = vtb + (unsigned)(quad * 256 + cidx * 8);
    unsigned ptb  = (unsigned)(uintptr_t)(as3_ushort*)&Pt[w][0];
    unsigned va_p = ptb + (unsigned)(quad * 256 + cidx * 8);
    char* pwr = (char*)&Pt[w][0] + cidx * 32 + quad * 8;

    for (int it = 0; it < nt; ++it) {
        int cur = it & 1;
        int kvb = ck0 + it * 64;

        // ---- issue next-tile K+V prefetch into other buffer (lands during this tile) ----
        if (it + 1 < nt) {
            size_t nv = (size_t)(it + 1) * 64 * HD;
#pragma unroll
            for (int i = 0; i < 2; ++i) {
                __builtin_amdgcn_global_load_lds(
                    (as1_ushort*)(ksrc[i] + nv),
                    (as3_ushort*)&Klds[(cur ^ 1) * 4096 + (w * 2 + i) * 512], 16, 0, 0);
                __builtin_amdgcn_global_load_lds(
                    (as1_ushort*)(vsrc[i] + nv),
                    (as3_ushort*)&Vt[(cur ^ 1) * 4096 + (w * 2 + i) * 512], 16, 0, 0);
            }
        }

        // ---- QK^T from LDS (conflict-free tiled ds_read_b128) ----
        bf16x8 kb[4][2];
#pragma unroll
        for (int ht = 0; ht < 4; ++ht)
#pragma unroll
            for (int ka = 0; ka < 2; ++ka)
                kb[ht][ka] = *reinterpret_cast<bf16x8*>(
                    &Klds[cur * 4096 + ht * 1024 + ka * 512 + quad * 128 + cidx * 8]);
        f32x4 sc[4];
#pragma unroll
        for (int ht = 0; ht < 4; ++ht) {
            f32x4 cacc = zero;
            cacc = __builtin_amdgcn_mfma_f32_16x16x32_bf16(qa[0], kb[ht][0], cacc, 0, 0, 0);
            cacc = __builtin_amdgcn_mfma_f32_16x16x32_bf16(qa[1], kb[ht][1], cacc, 0, 0, 0);
            sc[ht] = cacc;
        }

        // ---- causal mask (diagonal tile only; Q pre-scaled by 1/8) ----
        if (kvb + 63 > qrow0) {
#pragma unroll
            for (int ht = 0; ht < 4; ++ht)
#pragma unroll
                for (int i = 0; i < 4; ++i)
                    if (kvb + ht * 16 + cidx > qrow0 + quad * 4 + i) sc[ht][i] = -1e30f;
        }

        // ---- row max via DPP rotations (16-lane all-reduce, VALU-speed) ----
        float mx[4];
#pragma unroll
        for (int i = 0; i < 4; ++i) {
            mx[i] = fmaxf(fmaxf(sc[0][i], sc[1][i]), fmaxf(sc[2][i], sc[3][i]));
            mx[i] = rowmax16_dpp(mx[i]);
        }

        // ---- defer-max (T13): rescale only when max grew by > 8 ----
        bool need = false;
#pragma unroll
        for (int i = 0; i < 4; ++i) need |= (mx[i] > m_run[i] + 8.f);
        if (__any(need)) {
#pragma unroll
            for (int i = 0; i < 4; ++i) {
                float mnew = fmaxf(m_run[i], mx[i]);
                float scl = __expf(m_run[i] - mnew);
                m_run[i] = mnew;
#pragma unroll
                for (int dt = 0; dt < 4; ++dt) acc[dt][i] *= scl;
                acc_l[i] *= scl;
            }
        }
#pragma unroll
        for (int i = 0; i < 4; ++i)
#pragma unroll
            for (int ht = 0; ht < 4; ++ht) sc[ht][i] = __expf(sc[ht][i] - m_run[i]);

        // ---- P^T -> LDS: pack pairs with cvt_pk, 4x ds_write_b64 ----
#pragma unroll
        for (int ht = 0; ht < 4; ++ht) {
            u32x2 pk;
            pk[0] = cvt_pk_bf16(sc[ht][0], sc[ht][1]);
            pk[1] = cvt_pk_bf16(sc[ht][2], sc[ht][3]);
            *reinterpret_cast<u32x2*>(pwr + ht * 512) = pk;
        }
        asm volatile("" ::: "memory");

        // ---- group A: P trs + V trs (dt0,dt1) ----
        unsigned va = va_base + (unsigned)(cur * 8192);
        u32x2 pt_[4];
        TRR(pt_[0], va_p, 0);    TRR(pt_[1], va_p, 128);
        TRR(pt_[2], va_p, 1024); TRR(pt_[3], va_p, 1152);
        u32x2 tv[2][4];
        TRR(tv[0][0], va, 0);    TRR(tv[0][1], va, 128);
        TRR(tv[0][2], va, 1024); TRR(tv[0][3], va, 1152);
        TRR(tv[1][0], va, 2048); TRR(tv[1][1], va, 2176);
        TRR(tv[1][2], va, 3072); TRR(tv[1][3], va, 3200);
        asm volatile("s_waitcnt lgkmcnt(0)" ::: "memory");
        __builtin_amdgcn_sched_barrier(0);

        union { u32x2 a[2]; bf16x8 v; } up0, up1;
        up0.a[0] = pt_[0]; up0.a[1] = pt_[1];
        up1.a[0] = pt_[2]; up1.a[1] = pt_[3];
        bf16x8 pa0 = up0.v, pa1 = up1.v;

        __builtin_amdgcn_s_setprio(1);
        acc_l = __builtin_amdgcn_mfma_f32_16x16x32_bf16(pa0, ones, acc_l, 0, 0, 0);
        acc_l = __builtin_amdgcn_mfma_f32_16x16x32_bf16(pa1, ones, acc_l, 0, 0, 0);
#pragma unroll
        for (int dt = 0; dt < 2; ++dt) {
            union { u32x2 a[2]; bf16x8 v; } u0, u1;
            u0.a[0] = tv[dt][0]; u0.a[1] = tv[dt][1];
            u1.a[0] = tv[dt][2]; u1.a[1] = tv[dt][3];
            acc[dt] = __builtin_amdgcn_mfma_f32_16x16x32_bf16(pa0, u0.v, acc[dt], 0, 0, 0);
            acc[dt] = __builtin_amdgcn_mfma_f32_16x16x32_bf16(pa1, u1.v, acc[dt], 0, 0, 0);
        }
        __builtin_amdgcn_s_setprio(0);

        // ---- group B: V trs (dt2,dt3) ----
        u32x2 tw[2][4];
        TRR(tw[0][0], va, 4096); TRR(tw[0][1], va, 4224);
        TRR(tw[0][2], va, 5120); TRR(tw[0][3], va, 5248);
        TRR(tw[1][0], va, 6144); TRR(tw[1][1], va, 6272);
        TRR(tw[1][2], va, 7168); TRR(tw[1][3], va, 7296);
        asm volatile("s_waitcnt lgkmcnt(0)" ::: "memory");
        __builtin_amdgcn_sched_barrier(0);

        __builtin_amdgcn_s_setprio(1);
#pragma unroll
        for (int dt = 0; dt < 2; ++dt) {
            union { u32x2 a[2]; bf16x8 v; } u0, u1;
            u0.a[0] = tw[dt][0]; u0.a[1] = tw[dt][1];
            u1.a[0] = tw[dt][2]; u1.a[1] = tw[dt][3];
            acc[dt + 2] = __builtin_amdgcn_mfma_f32_16x16x32_bf16(pa0, u0.v, acc[dt + 2], 0, 0, 0);
            acc[dt + 2] = __builtin_amdgcn_mfma_f32_16x16x32_bf16(pa1, u1.v, acc[dt + 2], 0, 0, 0);
        }
        __builtin_amdgcn_s_setprio(0);

        // prefetch had the whole tile to land; drain + sync
        asm volatile("s_waitcnt vmcnt(0)" ::: "memory");
        __syncthreads();
    }

    // ---- partial epilogue (unnormalized) ----
#pragma unroll
    for (int dt = 0; dt < 4; ++dt)
#pragma unroll
        for (int i = 0; i < 4; ++i) {
            int row = w * 16 + quad * 4 + i;
            part_acc[((size_t)p * 64 + row) * 64 + dt * 16 + cidx] = f2bf(acc[dt][i]);
        }
    if (cidx == 0) {
#pragma unroll
        for (int i = 0; i < 4; ++i) {
            int row = w * 16 + quad * 4 + i;
            part_ml[((size_t)p * 64 + row) * 2 + 0] = m_run[i];
            part_ml[((size_t)p * 64 + row) * 2 + 1] = acc_l[i];
        }
    }
}

// ---------- combine partials -> attention output [B*S][HIDN] bf16 ----------
__global__ __launch_bounds__(256) void k_combine(const unsigned short* __restrict__ part_acc,
                                                 const float* __restrict__ part_ml,
                                                 unsigned short* __restrict__ a_out) {
    int idx = blockIdx.x * 256 + threadIdx.x;  // MTOT*NH*HD
    int d = idx & 63;
    int tmp = idx >> 6;
    int h = tmp % NH;
    int m_ = tmp / NH;           // b*SS + s
    int s = m_ & 2047;
    int qt = s >> 6, row = s & 63;
    int g = qt >> 3, r = qt & 7;
    int off = 4 * g * (g + 1) + r * (g + 1);
    int C = g + 1;
    int pb = ((m_ >> 11) * NH + h) * NCHUNK + off;

    float2 ml[4];
    float M = -1e30f;
#pragma unroll
    for (int cc = 0; cc < 4; ++cc) {
        if (cc < C) {
            ml[cc] = *reinterpret_cast<const float2*>(&part_ml[((size_t)(pb + cc) * 64 + row) * 2]);
            M = fmaxf(M, ml[cc].x);
        } else {
            ml[cc] = make_float2(-1e30f, 0.f);
        }
    }
    float L = 0.f, O = 0.f;
#pragma unroll
    for (int cc = 0; cc < 4; ++cc) {
        if (cc < C) {
            float wgt = __expf(ml[cc].x - M);
            L += ml[cc].y * wgt;
            O += bf2f(part_acc[((size_t)(pb + cc) * 64 + row) * 64 + d]) * wgt;
        }
    }
    a_out[(size_t)m_ * HIDN + h * 64 + d] = f2bf(O / L);
}

extern "C" void kernel_launch(void* const* d_in, const int* in_sizes, int n_in,
                              void* d_out, int out_size, void* d_ws, size_t ws_size,
                              hipStream_t stream) {
    (void)in_sizes; (void)n_in; (void)out_size; (void)ws_size;
    const float* h_f  = (const float*)d_in[0];
    const int*   pos  = (const int*)d_in[1];
    const float* Wq_f = (const float*)d_in[2];
    const float* Wk_f = (const float*)d_in[3];
    const float* Wv_f = (const float*)d_in[4];
    const float* Wo_f = (const float*)d_in[5];
    float* out = (float*)d_out;

    char* ws = (char*)d_ws;
    size_t off = 0;
    auto alloc = [&](size_t bytes) -> void* {
        void* p = ws + off;
        off += (bytes + 255) & ~(size_t)255;
        return p;
    };
    // region 0: h_bf + qkv_rm, later reused as part_acc (dead after pack kernels)
    unsigned short* h_bf   = (unsigned short*)alloc((size_t)MTOT * HIDN * 2);      // 12.58MB
    unsigned short* qkv_rm = (unsigned short*)alloc((size_t)MTOT * NQKV * 2);      // 18.87MB
    unsigned short* part_acc = h_bf;   // 48*80 * 64*64 * 2B = 31.46MB, fits exactly
    unsigned short* qkv_w  = (unsigned short*)alloc((size_t)NQKV * HIDN * 2);
    unsigned short* Wo_bf  = (unsigned short*)alloc((size_t)HIDN * NH * HD * 2);
    unsigned short* q_p    = (unsigned short*)alloc((size_t)MTOT * NH * HD * 2);
    unsigned short* k_p    = (unsigned short*)alloc((size_t)MTOT * NKV * HD * 2);
    unsigned short* v_p    = (unsigned short*)alloc((size_t)MTOT * NKV * HD * 2);
    unsigned short* a_out  = (unsigned short*)alloc((size_t)MTOT * HIDN * 2);
    float* cosT = (float*)alloc((size_t)SS * 32 * 4);
    float* sinT = (float*)alloc((size_t)SS * 32 * 4);
    float* part_ml = (float*)alloc((size_t)BB * NH * NCHUNK * 64 * 2 * 4);

    k_cast<<<(MTOT * HIDN / 4 + 255) / 256, 256, 0, stream>>>(h_f, h_bf, MTOT * HIDN / 4);
    k_cast<<<(HIDN * HIDN / 4 + 255) / 256, 256, 0, stream>>>(Wq_f, qkv_w, HIDN * HIDN / 4);
    k_cast<<<(NKV * HD * HIDN / 4 + 255) / 256, 256, 0, stream>>>(
        Wk_f, qkv_w + (size_t)HIDN * HIDN, NKV * HD * HIDN / 4);
    k_cast<<<(NKV * HD * HIDN / 4 + 255) / 256, 256, 0, stream>>>(
        Wv_f, qkv_w + (size_t)(HIDN + NKV * HD) * HIDN, NKV * HD * HIDN / 4);
    k_cast<<<(HIDN * NH * HD / 4 + 255) / 256, 256, 0, stream>>>(Wo_f, Wo_bf, HIDN * NH * HD / 4);
    k_rope_table<<<(SS * 32 + 255) / 256, 256, 0, stream>>>(cosT, sinT);

    // fused QKV projection
    gemm_bt<unsigned short><<<dim3(NQKV / 128, MTOT / 128), 256, 0, stream>>>(
        h_bf, qkv_w, qkv_rm, NQKV, HIDN);

    k_rope_pack<<<(MTOT * NH * 32) / 256, 256, 0, stream>>>(
        qkv_rm, NQKV, 0, pos, cosT, sinT, q_p, NH, 0.125f);   // Q pre-scaled by 1/sqrt(64)
    k_rope_pack<<<(MTOT * NKV * 32) / 256, 256, 0, stream>>>(
        qkv_rm, NQKV, NH * HD, pos, cosT, sinT, k_p, NKV, 1.0f);
    k_pack_v<<<(MTOT * NKV * HD) / 256, 256, 0, stream>>>(
        qkv_rm, NQKV, NH * HD + NKV * HD, v_p);

    // split-KV attention + combine (part_acc overlays the now-dead h_bf/qkv_rm region)
    k_attn<<<dim3(NCHUNK, NH, BB), 256, 0, stream>>>(q_p, k_p, v_p, part_acc, part_ml);
    k_combine<<<(MTOT * NH * HD) / 256, 256, 0, stream>>>(part_acc, part_ml, a_out);

    gemm_bt<float><<<dim3(HIDN / 128, MTOT / 128), 256, 0, stream>>>(
        a_out, Wo_bf, out, HIDN, HIDN);
}

// Round 6
// 232.431 us; speedup vs baseline: 1.8239x; 1.0222x over previous
//
#include <hip/hip_runtime.h>
#include <hip/hip_bf16.h>

// ---- problem constants ----
#define HIDN 1536
#define NH   24
#define NKV  6
#define HD   64
#define BB   2
#define SS   2048
#define MTOT (BB*SS)   // 4096
#define NQKV 2304      // NH*HD + 2*NKV*HD
#define NCHUNK 80      // sum over qt=0..31 of (qt/8+1)

typedef __bf16 bf16x8 __attribute__((ext_vector_type(8)));
typedef float  f32x4  __attribute__((ext_vector_type(4)));
typedef unsigned short u16x8 __attribute__((ext_vector_type(8)));
typedef unsigned int   u32x2 __attribute__((ext_vector_type(2)));

typedef __attribute__((address_space(1))) const unsigned short as1_ushort;
typedef __attribute__((address_space(3))) unsigned short as3_ushort;

__device__ inline float bf2f(unsigned short u) {
    unsigned v = (unsigned)u << 16; float f; __builtin_memcpy(&f, &v, 4); return f;
}
__device__ inline unsigned short f2bf(float f) {
    unsigned u; __builtin_memcpy(&u, &f, 4);
    u = (u + 0x7FFFu + ((u >> 16) & 1u)) >> 16;
    return (unsigned short)u;
}
__device__ inline unsigned cvt_pk_bf16(float lo, float hi) {
    unsigned r;
    asm("v_cvt_pk_bf16_f32 %0, %1, %2" : "=v"(r) : "v"(lo), "v"(hi));
    return r;
}
// all-reduce max within each 16-lane DPP row via row_ror rotations (VALU-speed)
__device__ inline float rowmax16_dpp(float x) {
    int v, r;
    v = __float_as_int(x);
    r = __builtin_amdgcn_update_dpp(v, v, 0x121, 0xF, 0xF, false);  // row_ror:1
    x = fmaxf(x, __int_as_float(r));
    v = __float_as_int(x);
    r = __builtin_amdgcn_update_dpp(v, v, 0x122, 0xF, 0xF, false);  // row_ror:2
    x = fmaxf(x, __int_as_float(r));
    v = __float_as_int(x);
    r = __builtin_amdgcn_update_dpp(v, v, 0x124, 0xF, 0xF, false);  // row_ror:4
    x = fmaxf(x, __int_as_float(r));
    v = __float_as_int(x);
    r = __builtin_amdgcn_update_dpp(v, v, 0x128, 0xF, 0xF, false);  // row_ror:8
    x = fmaxf(x, __int_as_float(r));
    return x;
}
__device__ inline void store_out(float* p, float v) { *p = v; }
__device__ inline void store_out(unsigned short* p, float v) { *p = f2bf(v); }

// ---------- cast f32 -> bf16, 4 elems/thread ----------
__global__ __launch_bounds__(256) void k_cast(const float* __restrict__ in,
                                              unsigned short* __restrict__ out, int n4) {
    int i = blockIdx.x * 256 + threadIdx.x;
    if (i >= n4) return;
    float4 v = reinterpret_cast<const float4*>(in)[i];
    ushort4 o;
    o.x = f2bf(v.x); o.y = f2bf(v.y); o.z = f2bf(v.z); o.w = f2bf(v.w);
    reinterpret_cast<ushort4*>(out)[i] = o;
}

// ---------- all 4 weight casts in one launch ----------
__global__ __launch_bounds__(256) void k_castw(const float* __restrict__ Wq,
                                               const float* __restrict__ Wk,
                                               const float* __restrict__ Wv,
                                               const float* __restrict__ Wo,
                                               unsigned short* __restrict__ qkv_w,
                                               unsigned short* __restrict__ Wo_bf) {
    int i = blockIdx.x * 256 + threadIdx.x;   // total = 2*nQ + 2*nK = 1474560 exactly
    const int nQ = HIDN * HIDN / 4, nK = NKV * HD * HIDN / 4;
    const float* src; unsigned short* dst; int j;
    if (i < nQ)               { src = Wq; dst = qkv_w;                          j = i; }
    else if (i < nQ + nK)     { src = Wk; dst = qkv_w + (size_t)nQ * 4;         j = i - nQ; }
    else if (i < nQ + 2 * nK) { src = Wv; dst = qkv_w + (size_t)(nQ + nK) * 4;  j = i - nQ - nK; }
    else                      { src = Wo; dst = Wo_bf;                          j = i - nQ - 2 * nK; }
    float4 v = reinterpret_cast<const float4*>(src)[j];
    ushort4 o;
    o.x = f2bf(v.x); o.y = f2bf(v.y); o.z = f2bf(v.z); o.w = f2bf(v.w);
    reinterpret_cast<ushort4*>(dst)[j] = o;
}

// ---------- RoPE (cos,sin) float2 table: [S][32] ----------
__global__ __launch_bounds__(256) void k_cs_table(float2* __restrict__ cs) {
    int i = blockIdx.x * 256 + threadIdx.x;
    if (i >= SS * 32) return;
    int s = i >> 5, f = i & 31;
    double inv = pow(10000.0, -(double)f / 32.0);
    double ang = (double)s * inv;
    cs[i] = make_float2((float)cos(ang), (float)sin(ang));
}

// ---------- GEMM (m97 structure): C[M,N] = A[M,K](bf16) @ Bt[N,K](bf16)^T ----------
template <typename OutT>
__global__ __launch_bounds__(256) void gemm_bt(const unsigned short* __restrict__ A,
                                               const unsigned short* __restrict__ Bt,
                                               OutT* __restrict__ C,
                                               int N, int K) {
    __shared__ unsigned short Alds[128 * 32];
    __shared__ unsigned short Blds[128 * 32];
    int t = threadIdx.x;
    int lane = t & 63, w = t >> 6;
    int m0 = blockIdx.y * 128, n0 = blockIdx.x * 128;
    int wm = (w >> 1) * 64, wn = (w & 1) * 64;
    int cidx = lane & 15, quad = lane >> 4;
    int srow = lane >> 2, scol = (lane & 3) * 8;

    f32x4 zero = {0.f, 0.f, 0.f, 0.f};
    f32x4 acc[4][4];
#pragma unroll
    for (int mi = 0; mi < 4; ++mi)
#pragma unroll
        for (int ni = 0; ni < 4; ++ni) acc[mi][ni] = zero;

    for (int k0 = 0; k0 < K; k0 += 32) {
        __syncthreads();
#pragma unroll
        for (int c = 0; c < 2; ++c) {
            int chunk = w + c * 4;
            int row = chunk * 16 + srow;
            __builtin_amdgcn_global_load_lds(
                (as1_ushort*)(A + (size_t)(m0 + row) * K + k0 + scol),
                (as3_ushort*)&Alds[chunk * 512], 16, 0, 0);
            __builtin_amdgcn_global_load_lds(
                (as1_ushort*)(Bt + (size_t)(n0 + row) * K + k0 + scol),
                (as3_ushort*)&Blds[chunk * 512], 16, 0, 0);
        }
        __syncthreads();
        bf16x8 af[4], bfr[4];
#pragma unroll
        for (int mi = 0; mi < 4; ++mi)
            af[mi] = *reinterpret_cast<bf16x8*>(&Alds[(wm + mi * 16 + cidx) * 32 + quad * 8]);
#pragma unroll
        for (int ni = 0; ni < 4; ++ni)
            bfr[ni] = *reinterpret_cast<bf16x8*>(&Blds[(wn + ni * 16 + cidx) * 32 + quad * 8]);
#pragma unroll
        for (int mi = 0; mi < 4; ++mi)
#pragma unroll
            for (int ni = 0; ni < 4; ++ni)
                acc[mi][ni] = __builtin_amdgcn_mfma_f32_16x16x32_bf16(af[mi], bfr[ni],
                                                                      acc[mi][ni], 0, 0, 0);
    }
#pragma unroll
    for (int mi = 0; mi < 4; ++mi)
#pragma unroll
        for (int ni = 0; ni < 4; ++ni)
#pragma unroll
            for (int i = 0; i < 4; ++i) {
                int row = m0 + wm + mi * 16 + quad * 4 + i;
                int col = n0 + wn + ni * 16 + cidx;
                store_out(&C[(size_t)row * N + col], acc[mi][ni][i]);
            }
}

// ---------- fused QKV GEMM: epilogue applies RoPE (+1/8 scale on Q) and packs ----------
// to q_p/k_p/v_p [B,H,S,HD]. Wave 64-col tile == one head; RoPE pair (d,d+32) ==
// (acc[mi][ni], acc[mi][ni+2]).
__global__ __launch_bounds__(256) void gemm_qkv(const unsigned short* __restrict__ A,
                                                const unsigned short* __restrict__ Bt,
                                                const int* __restrict__ pos_ids,
                                                const float2* __restrict__ cs,
                                                unsigned short* __restrict__ q_p,
                                                unsigned short* __restrict__ k_p,
                                                unsigned short* __restrict__ v_p) {
    __shared__ unsigned short Alds[128 * 32];
    __shared__ unsigned short Blds[128 * 32];
    int t = threadIdx.x;
    int lane = t & 63, w = t >> 6;
    int m0 = blockIdx.y * 128, n0 = blockIdx.x * 128;
    int wm = (w >> 1) * 64, wn = (w & 1) * 64;
    int cidx = lane & 15, quad = lane >> 4;
    int srow = lane >> 2, scol = (lane & 3) * 8;

    f32x4 zero = {0.f, 0.f, 0.f, 0.f};
    f32x4 acc[4][4];
#pragma unroll
    for (int mi = 0; mi < 4; ++mi)
#pragma unroll
        for (int ni = 0; ni < 4; ++ni) acc[mi][ni] = zero;

    for (int k0 = 0; k0 < HIDN; k0 += 32) {
        __syncthreads();
#pragma unroll
        for (int c = 0; c < 2; ++c) {
            int chunk = w + c * 4;
            int row = chunk * 16 + srow;
            __builtin_amdgcn_global_load_lds(
                (as1_ushort*)(A + (size_t)(m0 + row) * HIDN + k0 + scol),
                (as3_ushort*)&Alds[chunk * 512], 16, 0, 0);
            __builtin_amdgcn_global_load_lds(
                (as1_ushort*)(Bt + (size_t)(n0 + row) * HIDN + k0 + scol),
                (as3_ushort*)&Blds[chunk * 512], 16, 0, 0);
        }
        __syncthreads();
        bf16x8 af[4], bfr[4];
#pragma unroll
        for (int mi = 0; mi < 4; ++mi)
            af[mi] = *reinterpret_cast<bf16x8*>(&Alds[(wm + mi * 16 + cidx) * 32 + quad * 8]);
#pragma unroll
        for (int ni = 0; ni < 4; ++ni)
            bfr[ni] = *reinterpret_cast<bf16x8*>(&Blds[(wn + ni * 16 + cidx) * 32 + quad * 8]);
#pragma unroll
        for (int mi = 0; mi < 4; ++mi)
#pragma unroll
            for (int ni = 0; ni < 4; ++ni)
                acc[mi][ni] = __builtin_amdgcn_mfma_f32_16x16x32_bf16(af[mi], bfr[ni],
                                                                      acc[mi][ni], 0, 0, 0);
    }

    // ---- fused epilogue ----
    int colbase = n0 + wn;   // multiple of 64 -> exactly one head
    if (colbase >= NH * HD + NKV * HD) {        // V segment: plain pack
        int h = (colbase - (NH * HD + NKV * HD)) >> 6;
#pragma unroll
        for (int mi = 0; mi < 4; ++mi)
#pragma unroll
            for (int i = 0; i < 4; ++i) {
                int row = m0 + wm + mi * 16 + quad * 4 + i;
                int b = row >> 11, s = row & 2047;
                size_t base = ((size_t)(b * NKV + h) * SS + s) * 64;
#pragma unroll
                for (int ni = 0; ni < 4; ++ni)
                    v_p[base + ni * 16 + cidx] = f2bf(acc[mi][ni][i]);
            }
    } else {
        bool isQ = colbase < NH * HD;
        unsigned short* dst = isQ ? q_p : k_p;
        int h = isQ ? (colbase >> 6) : ((colbase - NH * HD) >> 6);
        int H = isQ ? NH : NKV;
        float scl = isQ ? 0.125f : 1.0f;   // Q pre-scaled by 1/sqrt(64)
#pragma unroll
        for (int mi = 0; mi < 4; ++mi)
#pragma unroll
            for (int i = 0; i < 4; ++i) {
                int row = m0 + wm + mi * 16 + quad * 4 + i;
                int b = row >> 11, s = row & 2047;
                int pos = pos_ids[row];
                float2 c1 = cs[pos * 32 + cidx];
                float2 c2 = cs[pos * 32 + 16 + cidx];
                size_t base = ((size_t)(b * H + h) * SS + s) * 64;
                float x10 = acc[mi][0][i], x20 = acc[mi][2][i];
                float x11 = acc[mi][1][i], x21 = acc[mi][3][i];
                dst[base + cidx]       = f2bf((x10 * c1.x - x20 * c1.y) * scl);
                dst[base + 32 + cidx]  = f2bf((x20 * c1.x + x10 * c1.y) * scl);
                dst[base + 16 + cidx]  = f2bf((x11 * c2.x - x21 * c2.y) * scl);
                dst[base + 48 + cidx]  = f2bf((x21 * c2.x + x11 * c2.y) * scl);
            }
    }
}

// ---------- split-KV flash attention ----------
// grid.x = 80 chunk-blocks per (b,h). 4 waves x 16 q-rows. K+V staged via
// global_load_lds (tiled layouts), double-buffered, prefetch 1 tile ahead.
// V tr-reads hoisted before softmax; single lgkm drain per tile (P only).
#define TRR(dst, ADDR, OFF) asm volatile("ds_read_b64_tr_b16 %0, %1 offset:" #OFF \
                                         : "=v"(dst) : "v"(ADDR))

__global__ __launch_bounds__(256, 4) void k_attn(const unsigned short* __restrict__ Qp,
                                                 const unsigned short* __restrict__ Kp,
                                                 const unsigned short* __restrict__ Vp,
                                                 unsigned short* __restrict__ part_acc,
                                                 float* __restrict__ part_ml) {
    int bxr = NCHUNK - 1 - (int)blockIdx.x;   // heavy (large qt) first
    int h = blockIdx.y, b = blockIdx.z;
    int kvh = h >> 2;
    int qt = 0, c = 0;
    {
        int g = (bxr >= 48) ? 3 : (bxr >= 24) ? 2 : (bxr >= 8) ? 1 : 0;
        int b0 = 4 * g * (g + 1);
        int idx = bxr - b0;
        qt = 8 * g + idx / (g + 1);
        c = idx % (g + 1);
    }
    int p = (b * NH + h) * NCHUNK + bxr;
    int qbase = qt * 64, ck0 = c * 512;
    int nt = min(8, qt + 1 - c * 8);

    int t = threadIdx.x, lane = t & 63, w = t >> 6;
    int cidx = lane & 15, quad = lane >> 4;
    int qrow0 = qbase + w * 16;

    const unsigned short* qptr  = Qp + ((size_t)(b * NH + h) * SS + qrow0) * HD;
    const unsigned short* kbase = Kp + (((size_t)(b * NKV + kvh) * SS) + ck0) * HD;
    const unsigned short* vbase = Vp + (((size_t)(b * NKV + kvh) * SS) + ck0) * HD;

    __shared__ unsigned short Klds[2 * 4096];    // 2 x 8KB tiled K [ht][ka][quad][cidx][8]
    __shared__ unsigned short Vt[2 * 4096];      // 2 x 8KB tiled V [d16][kv4][4][16]
    __shared__ unsigned short Pt[4][64 * 16];    // per-wave P^T

    const unsigned short* ksrc[2];
    const unsigned short* vsrc[2];
#pragma unroll
    for (int i = 0; i < 2; ++i) {
        int o = (w * 2 + i) * 512 + lane * 8;
        int kh = o >> 10, ka = (o >> 9) & 1, kq = (o >> 7) & 3, kc = (o >> 3) & 15;
        ksrc[i] = kbase + (kh * 16 + kc) * HD + ka * 32 + kq * 8;
        int r = o & 1023;
        int kv = ((r >> 6) << 2) | ((r >> 4) & 3);
        int d  = ((o >> 10) << 4) | (r & 15);
        vsrc[i] = vbase + kv * HD + d;
    }

    bf16x8 qa[2];
#pragma unroll
    for (int ka = 0; ka < 2; ++ka)
        qa[ka] = *reinterpret_cast<const bf16x8*>(qptr + (size_t)cidx * HD + ka * 32 + quad * 8);

    bf16x8 ones;
    {
        unsigned short ob = 0x3F80;  // bf16 1.0
        u16x8 ov;
#pragma unroll
        for (int j = 0; j < 8; ++j) ov[j] = ob;
        __builtin_memcpy(&ones, &ov, 16);
    }

    f32x4 zero = {0.f, 0.f, 0.f, 0.f};
    f32x4 acc[4], acc_l = zero;
    float m_run[4];
#pragma unroll
    for (int i = 0; i < 4; ++i) { acc[i] = zero; m_run[i] = -1e30f; }

    // prologue: stage K0,V0 into buf 0
#pragma unroll
    for (int i = 0; i < 2; ++i) {
        __builtin_amdgcn_global_load_lds((as1_ushort*)ksrc[i],
                                         (as3_ushort*)&Klds[(w * 2 + i) * 512], 16, 0, 0);
        __builtin_amdgcn_global_load_lds((as1_ushort*)vsrc[i],
                                         (as3_ushort*)&Vt[(w * 2 + i) * 512], 16, 0, 0);
    }
    asm volatile("s_waitcnt vmcnt(0)" ::: "memory");
    __syncthreads();

    unsigned vtb  = (unsigned)(uintptr_t)(as3_ushort*)&Vt[0];
    unsigned va_base = vtb + (unsigned)(quad * 256 + cidx * 8);
    unsigned ptb  = (unsigned)(uintptr_t)(as3_ushort*)&Pt[w][0];
    unsigned va_p = ptb + (unsigned)(quad * 256 + cidx * 8);
    char* pwr = (char*)&Pt[w][0] + cidx * 32 + quad * 8;

    for (int it = 0; it < nt; ++it) {
        int cur = it & 1;
        int kvb = ck0 + it * 64;

        // ---- issue next-tile K+V prefetch ----
        if (it + 1 < nt) {
            size_t nv = (size_t)(it + 1) * 64 * HD;
#pragma unroll
            for (int i = 0; i < 2; ++i) {
                __builtin_amdgcn_global_load_lds(
                    (as1_ushort*)(ksrc[i] + nv),
                    (as3_ushort*)&Klds[(cur ^ 1) * 4096 + (w * 2 + i) * 512], 16, 0, 0);
                __builtin_amdgcn_global_load_lds(
                    (as1_ushort*)(vsrc[i] + nv),
                    (as3_ushort*)&Vt[(cur ^ 1) * 4096 + (w * 2 + i) * 512], 16, 0, 0);
            }
        }

        // ---- QK^T from LDS ----
        bf16x8 kb[4][2];
#pragma unroll
        for (int ht = 0; ht < 4; ++ht)
#pragma unroll
            for (int ka = 0; ka < 2; ++ka)
                kb[ht][ka] = *reinterpret_cast<bf16x8*>(
                    &Klds[cur * 4096 + ht * 1024 + ka * 512 + quad * 128 + cidx * 8]);
        f32x4 sc[4];
#pragma unroll
        for (int ht = 0; ht < 4; ++ht) {
            f32x4 cacc = zero;
            cacc = __builtin_amdgcn_mfma_f32_16x16x32_bf16(qa[0], kb[ht][0], cacc, 0, 0, 0);
            cacc = __builtin_amdgcn_mfma_f32_16x16x32_bf16(qa[1], kb[ht][1], cacc, 0, 0, 0);
            sc[ht] = cacc;
        }

        // ---- V tr-reads hoisted: V[cur] staged+drained last iteration; latency hides
        // under mask/max/exp below ----
        unsigned va = va_base + (unsigned)(cur * 8192);
        u32x2 tv[4][4];
        TRR(tv[0][0], va, 0);    TRR(tv[0][1], va, 128);
        TRR(tv[0][2], va, 1024); TRR(tv[0][3], va, 1152);
        TRR(tv[1][0], va, 2048); TRR(tv[1][1], va, 2176);
        TRR(tv[1][2], va, 3072); TRR(tv[1][3], va, 3200);
        TRR(tv[2][0], va, 4096); TRR(tv[2][1], va, 4224);
        TRR(tv[2][2], va, 5120); TRR(tv[2][3], va, 5248);
        TRR(tv[3][0], va, 6144); TRR(tv[3][1], va, 6272);
        TRR(tv[3][2], va, 7168); TRR(tv[3][3], va, 7296);

        // ---- causal mask (diagonal tile only; Q pre-scaled by 1/8) ----
        if (kvb + 63 > qrow0) {
#pragma unroll
            for (int ht = 0; ht < 4; ++ht)
#pragma unroll
                for (int i = 0; i < 4; ++i)
                    if (kvb + ht * 16 + cidx > qrow0 + quad * 4 + i) sc[ht][i] = -1e30f;
        }

        // ---- row max via DPP rotations ----
        float mx[4];
#pragma unroll
        for (int i = 0; i < 4; ++i) {
            mx[i] = fmaxf(fmaxf(sc[0][i], sc[1][i]), fmaxf(sc[2][i], sc[3][i]));
            mx[i] = rowmax16_dpp(mx[i]);
        }

        // ---- defer-max (T13) ----
        bool need = false;
#pragma unroll
        for (int i = 0; i < 4; ++i) need |= (mx[i] > m_run[i] + 8.f);
        if (__any(need)) {
#pragma unroll
            for (int i = 0; i < 4; ++i) {
                float mnew = fmaxf(m_run[i], mx[i]);
                float scl = __expf(m_run[i] - mnew);
                m_run[i] = mnew;
#pragma unroll
                for (int dt = 0; dt < 4; ++dt) acc[dt][i] *= scl;
                acc_l[i] *= scl;
            }
        }
#pragma unroll
        for (int i = 0; i < 4; ++i)
#pragma unroll
            for (int ht = 0; ht < 4; ++ht) sc[ht][i] = __expf(sc[ht][i] - m_run[i]);

        // ---- P^T -> LDS (cvt_pk + 4x ds_write_b64), then P tr-reads ----
#pragma unroll
        for (int ht = 0; ht < 4; ++ht) {
            u32x2 pk;
            pk[0] = cvt_pk_bf16(sc[ht][0], sc[ht][1]);
            pk[1] = cvt_pk_bf16(sc[ht][2], sc[ht][3]);
            *reinterpret_cast<u32x2*>(pwr + ht * 512) = pk;
        }
        asm volatile("" ::: "memory");
        u32x2 pt_[4];
        TRR(pt_[0], va_p, 0);    TRR(pt_[1], va_p, 128);
        TRR(pt_[2], va_p, 1024); TRR(pt_[3], va_p, 1152);
        asm volatile("s_waitcnt lgkmcnt(0)" ::: "memory");
        __builtin_amdgcn_sched_barrier(0);

        union { u32x2 a[2]; bf16x8 v; } up0, up1;
        up0.a[0] = pt_[0]; up0.a[1] = pt_[1];
        up1.a[0] = pt_[2]; up1.a[1] = pt_[3];
        bf16x8 pa0 = up0.v, pa1 = up1.v;

        // ---- all MFMAs in one cluster ----
        __builtin_amdgcn_s_setprio(1);
        acc_l = __builtin_amdgcn_mfma_f32_16x16x32_bf16(pa0, ones, acc_l, 0, 0, 0);
        acc_l = __builtin_amdgcn_mfma_f32_16x16x32_bf16(pa1, ones, acc_l, 0, 0, 0);
#pragma unroll
        for (int dt = 0; dt < 4; ++dt) {
            union { u32x2 a[2]; bf16x8 v; } u0, u1;
            u0.a[0] = tv[dt][0]; u0.a[1] = tv[dt][1];
            u1.a[0] = tv[dt][2]; u1.a[1] = tv[dt][3];
            acc[dt] = __builtin_amdgcn_mfma_f32_16x16x32_bf16(pa0, u0.v, acc[dt], 0, 0, 0);
            acc[dt] = __builtin_amdgcn_mfma_f32_16x16x32_bf16(pa1, u1.v, acc[dt], 0, 0, 0);
        }
        __builtin_amdgcn_s_setprio(0);

        // prefetch had the whole tile to land; drain + sync
        asm volatile("s_waitcnt vmcnt(0)" ::: "memory");
        __syncthreads();
    }

    // ---- partial epilogue (unnormalized) ----
#pragma unroll
    for (int dt = 0; dt < 4; ++dt)
#pragma unroll
        for (int i = 0; i < 4; ++i) {
            int row = w * 16 + quad * 4 + i;
            part_acc[((size_t)p * 64 + row) * 64 + dt * 16 + cidx] = f2bf(acc[dt][i]);
        }
    if (cidx == 0) {
#pragma unroll
        for (int i = 0; i < 4; ++i) {
            int row = w * 16 + quad * 4 + i;
            part_ml[((size_t)p * 64 + row) * 2 + 0] = m_run[i];
            part_ml[((size_t)p * 64 + row) * 2 + 1] = acc_l[i];
        }
    }
}

// ---------- combine partials -> attention output [B*S][HIDN] bf16 ----------
__global__ __launch_bounds__(256) void k_combine(const unsigned short* __restrict__ part_acc,
                                                 const float* __restrict__ part_ml,
                                                 unsigned short* __restrict__ a_out) {
    int idx = blockIdx.x * 256 + threadIdx.x;  // MTOT*NH*HD
    int d = idx & 63;
    int tmp = idx >> 6;
    int h = tmp % NH;
    int m_ = tmp / NH;           // b*SS + s
    int s = m_ & 2047;
    int qt = s >> 6, row = s & 63;
    int g = qt >> 3, r = qt & 7;
    int off = 4 * g * (g + 1) + r * (g + 1);
    int C = g + 1;
    int pb = ((m_ >> 11) * NH + h) * NCHUNK + off;

    float2 ml[4];
    float M = -1e30f;
#pragma unroll
    for (int cc = 0; cc < 4; ++cc) {
        if (cc < C) {
            ml[cc] = *reinterpret_cast<const float2*>(&part_ml[((size_t)(pb + cc) * 64 + row) * 2]);
            M = fmaxf(M, ml[cc].x);
        } else {
            ml[cc] = make_float2(-1e30f, 0.f);
        }
    }
    float L = 0.f, O = 0.f;
#pragma unroll
    for (int cc = 0; cc < 4; ++cc) {
        if (cc < C) {
            float wgt = __expf(ml[cc].x - M);
            L += ml[cc].y * wgt;
            O += bf2f(part_acc[((size_t)(pb + cc) * 64 + row) * 64 + d]) * wgt;
        }
    }
    a_out[(size_t)m_ * HIDN + h * 64 + d] = f2bf(O / L);
}

extern "C" void kernel_launch(void* const* d_in, const int* in_sizes, int n_in,
                              void* d_out, int out_size, void* d_ws, size_t ws_size,
                              hipStream_t stream) {
    (void)in_sizes; (void)n_in; (void)out_size; (void)ws_size;
    const float* h_f  = (const float*)d_in[0];
    const int*   pos  = (const int*)d_in[1];
    const float* Wq_f = (const float*)d_in[2];
    const float* Wk_f = (const float*)d_in[3];
    const float* Wv_f = (const float*)d_in[4];
    const float* Wo_f = (const float*)d_in[5];
    float* out = (float*)d_out;

    char* ws = (char*)d_ws;
    size_t off = 0;
    auto alloc = [&](size_t bytes) -> void* {
        void* p = ws + off;
        off += (bytes + 255) & ~(size_t)255;
        return p;
    };
    // region 0: h_bf (12.58MB, dead after QKV gemm) overlaid by part_acc (31.46MB)
    unsigned short* region0 = (unsigned short*)alloc((size_t)48 * NCHUNK * 64 * 64 * 2);
    unsigned short* h_bf     = region0;
    unsigned short* part_acc = region0;
    unsigned short* qkv_w  = (unsigned short*)alloc((size_t)NQKV * HIDN * 2);
    unsigned short* Wo_bf  = (unsigned short*)alloc((size_t)HIDN * NH * HD * 2);
    unsigned short* q_p    = (unsigned short*)alloc((size_t)MTOT * NH * HD * 2);
    unsigned short* k_p    = (unsigned short*)alloc((size_t)MTOT * NKV * HD * 2);
    unsigned short* v_p    = (unsigned short*)alloc((size_t)MTOT * NKV * HD * 2);
    unsigned short* a_out  = (unsigned short*)alloc((size_t)MTOT * HIDN * 2);
    float2* cs = (float2*)alloc((size_t)SS * 32 * 8);
    float* part_ml = (float*)alloc((size_t)BB * NH * NCHUNK * 64 * 2 * 4);

    k_cast<<<(MTOT * HIDN / 4) / 256, 256, 0, stream>>>(h_f, h_bf, MTOT * HIDN / 4);
    k_castw<<<(2 * (HIDN * HIDN / 4) + 2 * (NKV * HD * HIDN / 4)) / 256, 256, 0, stream>>>(
        Wq_f, Wk_f, Wv_f, Wo_f, qkv_w, Wo_bf);
    k_cs_table<<<(SS * 32) / 256, 256, 0, stream>>>(cs);

    // fused QKV projection + RoPE + pack
    gemm_qkv<<<dim3(NQKV / 128, MTOT / 128), 256, 0, stream>>>(
        h_bf, qkv_w, pos, cs, q_p, k_p, v_p);

    // split-KV attention + combine (part_acc overlays the now-dead h_bf region)
    k_attn<<<dim3(NCHUNK, NH, BB), 256, 0, stream>>>(q_p, k_p, v_p, part_acc, part_ml);
    k_combine<<<(MTOT * NH * HD) / 256, 256, 0, stream>>>(part_acc, part_ml, a_out);

    gemm_bt<float><<<dim3(HIDN / 128, MTOT / 128), 256, 0, stream>>>(
        a_out, Wo_bf, out, HIDN, HIDN);
}